// Round 1
// baseline (1811.639 us; speedup 1.0000x reference)
//
#include <hip/hip_runtime.h>
#include <cstdint>
#include <cstddef>

typedef unsigned short u16;

// Problem constants
#define NN    100000
#define OUTD  8
#define KKP   20000
#define RR    16
#define EE    800000
#define KRR   (KKP*RR)   // 320000
#define KP    20096      // 157*128
#define NP    100096     // 782*128

typedef __bf16 v8bf __attribute__((ext_vector_type(8)));
typedef float  v4f  __attribute__((ext_vector_type(4)));

__device__ __forceinline__ float b2f(u16 u) {
    union { uint32_t i; float f; } v; v.i = (uint32_t)u << 16; return v.f;
}
__device__ __forceinline__ u16 f2b(float f) {
    union { float f; uint32_t i; } v; v.f = f;
    uint32_t i = v.i;
    return (u16)((i + 0x7fffu + ((i >> 16) & 1u)) >> 16);
}
__device__ __forceinline__ uint32_t pk2(float a, float b) {
    return (uint32_t)f2b(a) | ((uint32_t)f2b(b) << 16);
}

#define GLDS(g, l) __builtin_amdgcn_global_load_lds(                         \
    (const __attribute__((address_space(1))) void*)(g),                      \
    (__attribute__((address_space(3))) void*)(l), 16, 0, 0)

#define WAITVL(n) asm volatile("s_waitcnt vmcnt(" #n ") lgkmcnt(0)" ::: "memory")
#define BAR() __builtin_amdgcn_s_barrier()

// ---------------------------------------------------------------------------
// bf16 MFMA GEMM: C[M,Nout] = act(A[M,Ka] @ Wt[Nout,Ka]^T + bias)
// 128x128 tile, BK=32, 4 waves, 4x4 16x16x32 frags per wave.
// Depth-2 pipelined K-loop: GLDS operands triple-buffered with counted
// vmcnt (never drained to 0 in steady state); fp32-A path double-register
// staged (issue-early / convert+write-late), double-buffered in LDS.
// EPI: 0 none, 1 relu, 2 sigmoid.  OMODE: 1 bf16 out, 2 f32 out.
// A32: A is fp32, register-stage + convert into LDS (GLDS for B only).
// RETR: add o_retr/score extra K-rows of rp_W1 in epilogue (pre-activation).
// ---------------------------------------------------------------------------
template <int EPI, int OMODE, int A32, int RETR>
__launch_bounds__(256)
__global__ void gemm_bf_k(const void* __restrict__ Av, int lda, int M, int Ka,
                          const u16* __restrict__ Wt,
                          const float* __restrict__ bias,
                          void* __restrict__ Cv, int ldc,
                          const float* __restrict__ o_ex,
                          const float* __restrict__ s_ex,
                          const float* __restrict__ Wex)
{
    constexpr int NBA = A32 ? 2 : 3;
    __shared__ u16 As[NBA * 128 * 32];
    __shared__ u16 Bs[3 * 128 * 32];
    const int row0 = blockIdx.x * 128;
    const int col0 = blockIdx.y * 128;
    const int t    = threadIdx.x;
    const int lane = t & 63;
    const int w    = t >> 6;
    const int wm   = w & 1, wn = w >> 1;

    const int idx0 = t, idx1 = t + 256;
    const u16* Ab = (const u16*)Av;
    const float* Af = (const float*)Av;
    const u16* Ag0 = Ab + (size_t)(row0 + (idx0 >> 2)) * lda + (idx0 & 3) * 8;
    const u16* Ag1 = Ab + (size_t)(row0 + (idx1 >> 2)) * lda + (idx1 & 3) * 8;
    const float* Af0 = Af + (size_t)(row0 + (idx0 >> 2)) * lda + (idx0 & 3) * 8;
    const float* Af1 = Af + (size_t)(row0 + (idx1 >> 2)) * lda + (idx1 & 3) * 8;
    const u16* Bg0 = Wt + (size_t)(col0 + (idx0 >> 2)) * Ka + (idx0 & 3) * 8;
    const u16* Bg1 = Wt + (size_t)(col0 + (idx1 >> 2)) * Ka + (idx1 & 3) * 8;
    const int s0 = idx0 * 8, s1 = idx1 * 8;

    auto stageB = [&](int bi, int kk) {
        u16* bp = Bs + bi * (128 * 32);
        GLDS(Bg0 + kk, bp + s0);
        GLDS(Bg1 + kk, bp + s1);
    };
    auto stageA = [&](int bi, int kk) {
        u16* ap = As + bi * (128 * 32);
        GLDS(Ag0 + kk, ap + s0);
        GLDS(Ag1 + kk, ap + s1);
    };

    // Two in-flight fp32 A register sets (A32 path only)
    float4 P0, P1, P2, P3, Q0, Q1, Q2, Q3;
    auto loadP = [&](int kk) {
        P0 = *(const float4*)(Af0 + kk);     P1 = *(const float4*)(Af0 + kk + 4);
        P2 = *(const float4*)(Af1 + kk);     P3 = *(const float4*)(Af1 + kk + 4);
    };
    auto loadQ = [&](int kk) {
        Q0 = *(const float4*)(Af0 + kk);     Q1 = *(const float4*)(Af0 + kk + 4);
        Q2 = *(const float4*)(Af1 + kk);     Q3 = *(const float4*)(Af1 + kk + 4);
    };
    auto writeP = [&](int bi) {
        u16* ap = As + bi * (128 * 32);
        uint4 u0, u1;
        u0.x = pk2(P0.x, P0.y); u0.y = pk2(P0.z, P0.w);
        u0.z = pk2(P1.x, P1.y); u0.w = pk2(P1.z, P1.w);
        u1.x = pk2(P2.x, P2.y); u1.y = pk2(P2.z, P2.w);
        u1.z = pk2(P3.x, P3.y); u1.w = pk2(P3.z, P3.w);
        *(uint4*)(ap + s0) = u0;
        *(uint4*)(ap + s1) = u1;
    };
    auto writeQ = [&](int bi) {
        u16* ap = As + bi * (128 * 32);
        uint4 u0, u1;
        u0.x = pk2(Q0.x, Q0.y); u0.y = pk2(Q0.z, Q0.w);
        u0.z = pk2(Q1.x, Q1.y); u0.w = pk2(Q1.z, Q1.w);
        u1.x = pk2(Q2.x, Q2.y); u1.y = pk2(Q2.z, Q2.w);
        u1.z = pk2(Q3.x, Q3.y); u1.w = pk2(Q3.z, Q3.w);
        *(uint4*)(ap + s0) = u0;
        *(uint4*)(ap + s1) = u1;
    };

    v4f acc[4][4];
#pragma unroll
    for (int mi = 0; mi < 4; mi++)
#pragma unroll
        for (int ni = 0; ni < 4; ni++) acc[mi][ni] = 0.f;

    const int fr = lane & 15;
    const int fq = (lane >> 4) * 8;
    const int nk = Ka >> 5;

    // ---- prologue: stage tiles 0 and 1 ----
    if (A32) {
        loadP(0);                 // A(0) regs (oldest)
        stageB(0, 0);             // B(0)
        if (nk > 1) {
            loadQ(32);            // A(1) regs
            stageB(1, 32);        // B(1)
        }
        writeP(0);                // convert A(0) -> As[0] (auto-waits its loads)
        if (nk > 1) { WAITVL(6); }    // drain B(0); leave A(1)+B(1) in flight
        else        { WAITVL(0); }
    } else {
        stageA(0, 0); stageB(0, 0);
        if (nk > 1) { stageA(1, 32); stageB(1, 32); WAITVL(4); }
        else        { WAITVL(0); }
    }
    BAR();

    int rb = 0, sb = 2;
    for (int tI = 0; tI < nk; ++tI) {
        const bool st = (tI + 2) < nk;
        const int kk2 = (tI + 2) << 5;
        // ---- issue stage for tile t+2 (stays in flight across the barrier) ----
        if (st) {
            if (A32) {
                if (tI & 1) loadQ(kk2); else loadP(kk2);   // A(t+2) -> free set
                stageB(sb, kk2);
            } else {
                stageA(sb, kk2);
                stageB(sb, kk2);
            }
        }
        // ---- compute tile t ----
        const u16* Ar = As + (A32 ? (tI & 1) : rb) * (128 * 32);
        const u16* Br = Bs + rb * (128 * 32);
        v8bf af[4], bv[4];
#pragma unroll
        for (int mi = 0; mi < 4; mi++)
            af[mi] = *(const v8bf*)&Ar[(wm * 64 + mi * 16 + fr) * 32 + fq];
#pragma unroll
        for (int ni = 0; ni < 4; ni++)
            bv[ni] = *(const v8bf*)&Br[(wn * 64 + ni * 16 + fr) * 32 + fq];
#pragma unroll
        for (int mi = 0; mi < 4; mi++)
#pragma unroll
            for (int ni = 0; ni < 4; ni++)
                acc[mi][ni] = __builtin_amdgcn_mfma_f32_16x16x32_bf16(
                    af[mi], bv[ni], acc[mi][ni], 0, 0, 0);

        if (tI + 1 < nk) {
            if (A32) {
                // convert+write A(t+1) (loaded one full iter ago) -> As[(t+1)&1]
                if (tI & 1) writeP((tI + 1) & 1); else writeQ((tI + 1) & 1);
            }
            // Drain tile t+1's staging; leave tile t+2's (6 ops A32 / 4 GLDS) in flight.
            if (st) { if (A32) { WAITVL(6); } else { WAITVL(4); } }
            else    { WAITVL(0); }
            BAR();
        }
        rb = (rb == 2) ? 0 : rb + 1;
        sb = (sb == 2) ? 0 : sb + 1;
    }

    // D row = quad*4+reg, col = lane&15  [m89-verified]
    const int crow = wm * 64 + (lane >> 4) * 4;
    const int ccol = wn * 64 + (lane & 15);
    float bias_v[4];
#pragma unroll
    for (int ni = 0; ni < 4; ni++) bias_v[ni] = bias[col0 + ccol + ni * 16];

    u16*   Cb = (u16*)Cv;
    float* Cf = (float*)Cv;
#pragma unroll
    for (int mi = 0; mi < 4; mi++) {
#pragma unroll
        for (int reg = 0; reg < 4; reg++) {
            int r = row0 + crow + mi * 16 + reg;
            if (r >= M) continue;
            float ov[8], sv;
            if (RETR) {
#pragma unroll
                for (int u = 0; u < 8; u++) ov[u] = o_ex[(size_t)r * 8 + u];
                sv = s_ex[r];
            }
#pragma unroll
            for (int ni = 0; ni < 4; ni++) {
                int c = col0 + ccol + ni * 16;
                float v = acc[mi][ni][reg] + bias_v[ni];
                if (RETR) {
                    float e = sv * Wex[8 * 256 + c];
#pragma unroll
                    for (int u = 0; u < 8; u++) e = fmaf(ov[u], Wex[u * 256 + c], e);
                    v += e;
                }
                if (EPI == 1) v = fmaxf(v, 0.f);
                if (EPI == 2) v = 1.f / (1.f + expf(-v));
                if (OMODE == 1) Cb[(size_t)r * ldc + c] = f2b(v);
                else            Cf[(size_t)r * ldc + c] = v;
            }
        }
    }
}

// ---------------------------------------------------------------------------
// Weight prep
// ---------------------------------------------------------------------------
// Wt[o*Kpad + i] = (i<fi) ? W[i*ld + coloff + o] : 0   (256 outputs)
__global__ void wtpose_k(const float* __restrict__ W, int ld, int coloff,
                         int fi, int Kpad, u16* __restrict__ Wt)
{
    int g = blockIdx.x * 256 + threadIdx.x;
    if (g >= 256 * Kpad) return;
    int o = g / Kpad, i = g - o * Kpad;
    Wt[g] = f2b(i < fi ? W[(size_t)i * ld + coloff + o] : 0.f);
}

// Fused weight: Wt_out[j*256+i] = sum_m A[i,m] * Binw[m*ldb + off + j]
// Block 0 also writes bias_out[j] = bb[j] + sum_m ba[m]*Binw[m,j]
__global__ void wfuse_k(const float* __restrict__ A, const float* __restrict__ Binw,
                        int ldb, int off, const float* __restrict__ ba,
                        const float* __restrict__ bb,
                        u16* __restrict__ Wt_out, float* __restrict__ bias_out)
{
    __shared__ float As[256];
    __shared__ float bs[256];
    int i = blockIdx.x, j = threadIdx.x;
    As[j] = A[(size_t)i * 256 + j];
    bs[j] = ba[j];
    __syncthreads();
    float acc = 0.f, accb = 0.f;
    for (int m = 0; m < 256; m++) {
        float bv = Binw[(size_t)m * ldb + off + j];
        acc = fmaf(As[m], bv, acc);
        if (i == 0) accb = fmaf(bs[m], bv, accb);
    }
    Wt_out[(size_t)j * 256 + i] = f2b(acc);
    if (i == 0) bias_out[j] = bb[j] + accb;
}

__global__ void conv_f2b_k(const float* __restrict__ src, u16* __restrict__ dst, size_t n4)
{
    size_t g = (size_t)blockIdx.x * 256 + threadIdx.x;
    if (g >= n4) return;
    float4 v = ((const float4*)src)[g];
    ((ushort4*)dst)[g] = make_ushort4(f2b(v.x), f2b(v.y), f2b(v.z), f2b(v.w));
}

// gather h_cone[nids] -> acat cols 0..255 (bf16, ld 512)
__global__ void gather_hq_k(const float* __restrict__ hc, const int* __restrict__ nids,
                            u16* __restrict__ acat)
{
    int t = threadIdx.x;
    int k = blockIdx.x * 4 + (t >> 6);
    int c = t & 63;
    if (k >= KKP) return;
    int nid = nids[k];
    float4 v = ((const float4*)hc)[(size_t)nid * 64 + c];
    *(ushort4*)&acat[(size_t)k * 512 + c * 4] =
        make_ushort4(f2b(v.x), f2b(v.y), f2b(v.z), f2b(v.w));
}

// ---------------------------------------------------------------------------
// Fused attention: scores + softmax + apply.  khv [KRR,512]: k|v halves.
// Wave w handles head w (dims w*64..w*64+63 = thread t's column t).
// ---------------------------------------------------------------------------
__launch_bounds__(256)
__global__ void att_fused_k(const u16* __restrict__ qh, const u16* __restrict__ khv,
                            u16* __restrict__ ctx)
{
    int k = blockIdx.x;
    int t = threadIdx.x;
    int lane = t & 63;
    float qv = b2f(qh[(size_t)k * 256 + t]);
    const u16* kp = khv + (size_t)k * (RR * 512) + t;
    const u16* vp = kp + 256;
    float myscore = -1e30f;
#pragma unroll
    for (int r = 0; r < RR; r++) {
        float p = qv * b2f(kp[r * 512]);
#pragma unroll
        for (int off = 1; off < 64; off <<= 1) p += __shfl_xor(p, off);
        if (lane == r) myscore = p * 0.125f;   // 1/sqrt(64)
    }
    float m = (lane < RR) ? myscore : -1e30f;
#pragma unroll
    for (int off = 1; off < 16; off <<= 1) m = fmaxf(m, __shfl_xor(m, off));
    float pe = (lane < RR) ? expf(myscore - m) : 0.f;
    float ssum = pe;
#pragma unroll
    for (int off = 1; off < 16; off <<= 1) ssum += __shfl_xor(ssum, off);
    float pn = pe / ssum;                      // valid on lanes 0..15
    float acc = 0.f;
#pragma unroll
    for (int r = 0; r < RR; r++) {
        float ar = __shfl(pn, r);
        acc = fmaf(ar, b2f(vp[r * 512]), acc);
    }
    ctx[(size_t)k * 256 + t] = f2b(acc);
}

// ---------------------------------------------------------------------------
// Scatter (last-write-wins)
// ---------------------------------------------------------------------------
__global__ void winner_k(const int* __restrict__ nids, int* __restrict__ winner)
{
    int gid = blockIdx.x * 256 + threadIdx.x;
    if (gid < KKP) atomicMax(&winner[nids[gid]], gid);
}

__global__ void scatter_h_k(const int* __restrict__ nids, const int* __restrict__ winner,
                            const float* __restrict__ hc, const float* __restrict__ gate,
                            const float* __restrict__ upd, u16* __restrict__ hb)
{
    int t = threadIdx.x;
    int k = blockIdx.x * 4 + (t >> 6);
    int c = t & 63;
    if (k >= KKP) return;
    int nid = nids[k];
    if (winner[nid] != k) return;
    float4 hv = ((const float4*)hc)[(size_t)nid * 64 + c];
    float4 gv = ((const float4*)gate)[(size_t)k * 64 + c];
    float4 uv = ((const float4*)upd)[(size_t)k * 64 + c];
    *(ushort4*)&hb[(size_t)nid * 256 + c * 4] = make_ushort4(
        f2b(hv.x + gv.x * uv.x), f2b(hv.y + gv.y * uv.y),
        f2b(hv.z + gv.z * uv.z), f2b(hv.w + gv.w * uv.w));
}

// ---------------------------------------------------------------------------
// CSR build
// ---------------------------------------------------------------------------
__global__ void edge_count_k(const int* __restrict__ dst, int* __restrict__ cnt, int e)
{
    int gid = blockIdx.x * 256 + threadIdx.x;
    if (gid < e) atomicAdd(&cnt[dst[gid]], 1);
}

__global__ void isd_k(const int* __restrict__ cnt, float* __restrict__ isd, int n)
{
    int gid = blockIdx.x * 256 + threadIdx.x;
    if (gid < n) isd[gid] = rsqrtf((float)(cnt[gid] + 1));
}

#define SCANB 1024
__global__ void scan1_k(const int* __restrict__ in, int* __restrict__ out,
                        int* __restrict__ bsums, int n)
{
    __shared__ int s[SCANB];
    int tid = threadIdx.x;
    int gid = blockIdx.x * SCANB + tid;
    int v = (gid < n) ? in[gid] : 0;
    s[tid] = v;
    __syncthreads();
    for (int off = 1; off < SCANB; off <<= 1) {
        int add = (tid >= off) ? s[tid - off] : 0;
        __syncthreads();
        s[tid] += add;
        __syncthreads();
    }
    if (gid < n) out[gid] = s[tid] - v;
    if (tid == SCANB - 1) bsums[blockIdx.x] = s[tid];
}

__global__ void scan2_k(int* bsums, int nb)
{
    if (threadIdx.x == 0 && blockIdx.x == 0) {
        int run = 0;
        for (int i = 0; i < nb; i++) { int v = bsums[i]; bsums[i] = run; run += v; }
    }
}

__global__ void scan3_k(int* __restrict__ out, const int* __restrict__ bsums, int n, int total)
{
    int gid = blockIdx.x * SCANB + threadIdx.x;
    if (gid < n) out[gid] += bsums[blockIdx.x];
    if (gid == 0) out[n] = total;
}

__global__ void csr_scatter_k(const int* __restrict__ src, const int* __restrict__ dst,
                              const int* __restrict__ row_start, int* __restrict__ cursor,
                              const float* __restrict__ isd,
                              int* __restrict__ csr_src, float* __restrict__ csr_w, int e)
{
    int gid = blockIdx.x * 256 + threadIdx.x;
    if (gid < e) {
        int sP = src[gid], dP = dst[gid];
        int pos = row_start[dP] + atomicAdd(&cursor[dP], 1);
        csr_src[pos] = sP;
        csr_w[pos] = isd[sP] * isd[dP];
    }
}

// GCN aggregation: wave per node, ushort4 per lane (512B per row read)
template <int RELU>
__launch_bounds__(256)
__global__ void gnn_agg_k(const u16* __restrict__ x, const int* __restrict__ row_start,
                          const int* __restrict__ csr_src, const float* __restrict__ csr_w,
                          const float* __restrict__ isd, u16* __restrict__ outp)
{
    int node = blockIdx.x * 4 + (threadIdx.x >> 6);
    int lane = threadIdx.x & 63;
    if (node >= NN) return;
    float si = isd[node];
    float sii = si * si;
    ushort4 sv = ((const ushort4*)x)[(size_t)node * 64 + lane];
    float a0 = b2f(sv.x) * sii, a1 = b2f(sv.y) * sii;
    float a2 = b2f(sv.z) * sii, a3 = b2f(sv.w) * sii;
    int s0 = row_start[node], s1 = row_start[node + 1];
    for (int j = s0; j < s1; j++) {
        int sP = csr_src[j];
        float wv = csr_w[j];
        ushort4 v = ((const ushort4*)x)[(size_t)sP * 64 + lane];
        a0 = fmaf(b2f(v.x), wv, a0);
        a1 = fmaf(b2f(v.y), wv, a1);
        a2 = fmaf(b2f(v.z), wv, a2);
        a3 = fmaf(b2f(v.w), wv, a3);
    }
    if (RELU) {
        a0 = fmaxf(a0, 0.f); a1 = fmaxf(a1, 0.f);
        a2 = fmaxf(a2, 0.f); a3 = fmaxf(a3, 0.f);
    }
    ((ushort4*)outp)[(size_t)node * 64 + lane] =
        make_ushort4(f2b(a0), f2b(a1), f2b(a2), f2b(a3));
}

// head layer-2 + teacher add
__launch_bounds__(256)
__global__ void head_out_k(const u16* __restrict__ thid, const float* __restrict__ W2,
                           const float* __restrict__ b2, const float* __restrict__ teacher,
                           float* __restrict__ outp, int n)
{
    __shared__ float ts[32][257];
    __shared__ float w2s[256 * 8];
    int t = threadIdx.x;
    int rbase = blockIdx.x * 32;
    for (int i = t; i < 2048; i += 256) w2s[i] = W2[i];
    for (int i = t; i < 32 * 256; i += 256) {
        int rr = i >> 8, cc = i & 255;
        int gr = rbase + rr;
        ts[rr][cc] = (gr < n) ? b2f(thid[(size_t)gr * 256 + cc]) : 0.f;
    }
    __syncthreads();
    int rr = t >> 3, cc = t & 7;
    int gr = rbase + rr;
    if (gr >= n) return;
    float acc = b2[cc];
    for (int kk = 0; kk < 256; kk++)
        acc = fmaf(ts[rr][kk], w2s[kk * 8 + cc], acc);
    outp[(size_t)gr * 8 + cc] = teacher[(size_t)gr * 8 + cc] + acc;
}

// ---------------------------------------------------------------------------
// Host launcher
// ---------------------------------------------------------------------------
extern "C" void kernel_launch(void* const* d_in, const int* in_sizes, int n_in,
                              void* d_out, int out_size, void* d_ws, size_t ws_size,
                              hipStream_t stream)
{
    (void)in_sizes; (void)n_in; (void)out_size; (void)ws_size;
    const float* h_cone     = (const float*)d_in[0];
    const float* z_retr     = (const float*)d_in[1];
    const float* o_retr     = (const float*)d_in[2];
    const float* retr_score = (const float*)d_in[3];
    const float* teacher    = (const float*)d_in[4];
    const int*   nids       = (const int*)d_in[5];
    const int*   edge       = (const int*)d_in[6];
    const float* rp_W1 = (const float*)d_in[7];   const float* rp_b1 = (const float*)d_in[8];
    const float* rp_W2 = (const float*)d_in[9];   const float* rp_b2 = (const float*)d_in[10];
    const float* qp_W  = (const float*)d_in[11];  const float* qp_b  = (const float*)d_in[12];
    const float* inW   = (const float*)d_in[13];  const float* inB   = (const float*)d_in[14];
    const float* outW  = (const float*)d_in[15];  const float* outB  = (const float*)d_in[16];
    const float* gW1   = (const float*)d_in[17];  const float* gB1   = (const float*)d_in[18];
    const float* gW2   = (const float*)d_in[19];  const float* gB2   = (const float*)d_in[20];
    const float* uW1   = (const float*)d_in[21];  const float* uB1   = (const float*)d_in[22];
    const float* uW2   = (const float*)d_in[23];  const float* uB2   = (const float*)d_in[24];
    const float* gnW1  = (const float*)d_in[25];  const float* gnB1  = (const float*)d_in[26];
    const float* gnW2  = (const float*)d_in[27];  const float* gnB2  = (const float*)d_in[28];
    const float* hW1   = (const float*)d_in[29];  const float* hB1   = (const float*)d_in[30];
    const float* hW2   = (const float*)d_in[31];  const float* hB2   = (const float*)d_in[32];
    float* out = (float*)d_out;

    char* ws = (char*)d_ws;
    size_t off = 0;
    auto alloc = [&](size_t bytes) -> void* {
        void* p = ws + off;
        off = (off + bytes + 255) & ~(size_t)255;
        return p;
    };
    u16* hidden = (u16*)alloc((size_t)KRR * 256 * 2);   // rp1 out; GNN overlays later
    u16* khv    = (u16*)alloc((size_t)KRR * 512 * 2);   // [k|v]
    u16* qhb    = (u16*)alloc((size_t)KP * 256 * 2);
    u16* ctxb   = (u16*)alloc((size_t)KP * 256 * 2);
    u16* acat   = (u16*)alloc((size_t)KP * 512 * 2);
    u16* ghid   = (u16*)alloc((size_t)KP * 256 * 2);
    float* gate = (float*)alloc((size_t)KP * 256 * 4);
    u16* uhid   = (u16*)alloc((size_t)KP * 256 * 2);
    float* upd  = (float*)alloc((size_t)KP * 256 * 4);
    u16* wt_rp1 = (u16*)alloc(256 * 256 * 2);
    u16* wt_kv  = (u16*)alloc(512 * 256 * 2);
    u16* wt_qf  = (u16*)alloc(256 * 256 * 2);
    u16* wt_o   = (u16*)alloc(256 * 256 * 2);
    u16* wt_g1  = (u16*)alloc(256 * 512 * 2);
    u16* wt_g2  = (u16*)alloc(256 * 256 * 2);
    u16* wt_u1  = (u16*)alloc(256 * 256 * 2);
    u16* wt_u2  = (u16*)alloc(256 * 256 * 2);
    u16* wt_gn1 = (u16*)alloc(256 * 256 * 2);
    u16* wt_gn2 = (u16*)alloc(256 * 256 * 2);
    u16* wt_h1  = (u16*)alloc(256 * 256 * 2);
    float* bias_kv = (float*)alloc(512 * 4);
    float* bias_qf = (float*)alloc(256 * 4);
    int*   winner    = (int*)alloc(NN * 4);
    int*   cnt       = (int*)alloc(NN * 4);
    int*   cursor    = (int*)alloc(NN * 4);
    int*   row_start = (int*)alloc((NN + 1) * 4);
    int*   bsums     = (int*)alloc(1024 * 4);
    float* isd       = (float*)alloc(NN * 4);
    int*   csr_src   = (int*)alloc((size_t)EE * 4);
    float* csr_w     = (float*)alloc((size_t)EE * 4);

    // GNN stage overlays hidden (dead after kv GEMM): 3 buffers of NP rows
    const size_t NPE = (size_t)NP * 256;
    u16* gZ0 = hidden;            // hb -> x2
    u16* gZ1 = hidden + NPE;      // x1 -> h2
    u16* gZ2 = hidden + 2 * NPE;  // h1 -> thid

    const int* esrc = edge;
    const int* edst = edge + EE;

    auto wtp = [&](const float* W, int ld, int coloff, int fi, int Kpad, u16* Wt) {
        wtpose_k<<<(256 * Kpad + 255) / 256, 256, 0, stream>>>(W, ld, coloff, fi, Kpad, Wt);
    };

    // ---- CSR prep ----
    hipMemsetAsync(cnt, 0, NN * 4, stream);
    hipMemsetAsync(cursor, 0, NN * 4, stream);
    edge_count_k<<<(EE + 255) / 256, 256, 0, stream>>>(edst, cnt, EE);
    isd_k<<<(NN + 255) / 256, 256, 0, stream>>>(cnt, isd, NN);
    int nb = (NN + SCANB - 1) / SCANB;
    scan1_k<<<nb, SCANB, 0, stream>>>(cnt, row_start, bsums, NN);
    scan2_k<<<1, 64, 0, stream>>>(bsums, nb);
    scan3_k<<<nb, SCANB, 0, stream>>>(row_start, bsums, NN, EE);
    csr_scatter_k<<<(EE + 255) / 256, 256, 0, stream>>>(esrc, edst, row_start, cursor, isd,
                                                        csr_src, csr_w, EE);

    // ---- weight prep ----
    wtp(rp_W1, 256, 0, 256, 256, wt_rp1);                    // z-part only; extras in epilogue
    wfuse_k<<<256, 256, 0, stream>>>(rp_W2, inW, 768, 256, rp_b2, inB + 256, wt_kv, bias_kv);
    wfuse_k<<<256, 256, 0, stream>>>(rp_W2, inW, 768, 512, rp_b2, inB + 512,
                                     wt_kv + 256 * 256, bias_kv + 256);
    wfuse_k<<<256, 256, 0, stream>>>(qp_W, inW, 768, 0, qp_b, inB, wt_qf, bias_qf);
    wtp(outW, 256, 0, 256, 256, wt_o);
    wtp(gW1,  256, 0, 512, 512, wt_g1);
    wtp(gW2,  256, 0, 256, 256, wt_g2);
    wtp(uW1,  256, 0, 256, 256, wt_u1);
    wtp(uW2,  256, 0, 256, 256, wt_u2);
    wtp(gnW1, 256, 0, 256, 256, wt_gn1);
    wtp(gnW2, 256, 0, 256, 256, wt_gn2);
    wtp(hW1,  256, 0, 256, 256, wt_h1);
    gather_hq_k<<<(KKP + 3) / 4, 256, 0, stream>>>(h_cone, nids, acat);

    // ---- retrieval MLP layer 1 (fp32 A, retr extras in epilogue) ----
    gemm_bf_k<1, 1, 1, 1><<<dim3(KRR / 128, 2), 256, 0, stream>>>(
        z_retr, 256, KRR, 256, wt_rp1, rp_b1, hidden, 256,
        o_retr, retr_score, rp_W1 + 256 * 256);
    // ---- fused K|V projection: khv = hidden @ [W2@Wk | W2@Wv] ----
    gemm_bf_k<0, 1, 0, 0><<<dim3(KRR / 128, 4), 256, 0, stream>>>(
        hidden, 256, KRR, 256, wt_kv, bias_kv, khv, 512, nullptr, nullptr, nullptr);
    // ---- fused query projection ----
    gemm_bf_k<0, 1, 0, 0><<<dim3((KKP + 127) / 128, 2), 256, 0, stream>>>(
        acat, 512, KKP, 256, wt_qf, bias_qf, qhb, 256, nullptr, nullptr, nullptr);

    // ---- attention (fused scores+softmax+apply) ----
    att_fused_k<<<KKP, 256, 0, stream>>>(qhb, khv, ctxb);
    gemm_bf_k<0, 1, 0, 0><<<dim3((KKP + 127) / 128, 2), 256, 0, stream>>>(
        ctxb, 256, KKP, 256, wt_o, outB, acat + 256, 512, nullptr, nullptr, nullptr);

    // ---- gate / update ----
    gemm_bf_k<1, 1, 0, 0><<<dim3((KKP + 127) / 128, 2), 256, 0, stream>>>(
        acat, 512, KKP, 512, wt_g1, gB1, ghid, 256, nullptr, nullptr, nullptr);
    gemm_bf_k<2, 2, 0, 0><<<dim3((KKP + 127) / 128, 2), 256, 0, stream>>>(
        ghid, 256, KKP, 256, wt_g2, gB2, gate, 256, nullptr, nullptr, nullptr);
    gemm_bf_k<1, 1, 0, 0><<<dim3((KKP + 127) / 128, 2), 256, 0, stream>>>(
        acat + 256, 512, KKP, 256, wt_u1, uB1, uhid, 256, nullptr, nullptr, nullptr);
    gemm_bf_k<0, 2, 0, 0><<<dim3((KKP + 127) / 128, 2), 256, 0, stream>>>(
        uhid, 256, KKP, 256, wt_u2, uB2, upd, 256, nullptr, nullptr, nullptr);

    // ---- scatter into hb (bf16 copy of h_cone, winner rows overwritten) ----
    conv_f2b_k<<<(int)(((size_t)NN * 64 + 255) / 256), 256, 0, stream>>>(
        h_cone, gZ0, (size_t)NN * 64);
    hipMemsetAsync(winner, 0xFF, NN * 4, stream);
    winner_k<<<(KKP + 255) / 256, 256, 0, stream>>>(nids, winner);
    scatter_h_k<<<(KKP + 3) / 4, 256, 0, stream>>>(nids, winner, h_cone, gate, upd, gZ0);

    // ---- cone GNN ----
    gemm_bf_k<0, 1, 0, 0><<<dim3((NN + 127) / 128, 2), 256, 0, stream>>>(
        gZ0, 256, NN, 256, wt_gn1, gnB1, gZ1, 256, nullptr, nullptr, nullptr);       // x1
    gnn_agg_k<1><<<(NN + 3) / 4, 256, 0, stream>>>(gZ1, row_start, csr_src, csr_w, isd, gZ2); // h1
    gemm_bf_k<0, 1, 0, 0><<<dim3((NN + 127) / 128, 2), 256, 0, stream>>>(
        gZ2, 256, NN, 256, wt_gn2, gnB2, gZ0, 256, nullptr, nullptr, nullptr);       // x2
    gnn_agg_k<0><<<(NN + 3) / 4, 256, 0, stream>>>(gZ0, row_start, csr_src, csr_w, isd, gZ1); // h2
    gemm_bf_k<1, 1, 0, 0><<<dim3((NN + 127) / 128, 2), 256, 0, stream>>>(
        gZ1, 256, NN, 256, wt_h1, hB1, gZ2, 256, nullptr, nullptr, nullptr);         // thid
    head_out_k<<<(NN + 31) / 32, 256, 0, stream>>>(gZ2, hW2, hB2, teacher, out, NN);
}

// Round 2
// 1610.192 us; speedup vs baseline: 1.1251x; 1.1251x over previous
//
#include <hip/hip_runtime.h>
#include <cstdint>
#include <cstddef>

typedef unsigned short u16;

// Problem constants
#define NN    100000
#define OUTD  8
#define KKP   20000
#define RR    16
#define EE    800000
#define KRR   (KKP*RR)   // 320000
#define KP    20096      // 157*128
#define NP    100096     // 782*128

typedef __bf16 v8bf __attribute__((ext_vector_type(8)));
typedef float  v4f  __attribute__((ext_vector_type(4)));

__device__ __forceinline__ float b2f(u16 u) {
    union { uint32_t i; float f; } v; v.i = (uint32_t)u << 16; return v.f;
}
__device__ __forceinline__ u16 f2b(float f) {
    union { float f; uint32_t i; } v; v.f = f;
    uint32_t i = v.i;
    return (u16)((i + 0x7fffu + ((i >> 16) & 1u)) >> 16);
}
__device__ __forceinline__ uint32_t pk2(float a, float b) {
    return (uint32_t)f2b(a) | ((uint32_t)f2b(b) << 16);
}

#define GLDS(g, l) __builtin_amdgcn_global_load_lds(                         \
    (const __attribute__((address_space(1))) void*)(g),                      \
    (__attribute__((address_space(3))) void*)(l), 16, 0, 0)

#define WAITVL(n) asm volatile("s_waitcnt vmcnt(" #n ") lgkmcnt(0)" ::: "memory")
#define BAR() __builtin_amdgcn_s_barrier()

// ---------------------------------------------------------------------------
// bf16 MFMA GEMM: C[M,Nout] = act(A[M,Ka] @ Wt[Nout,Ka]^T + bias)
// 128x128 tile, BK=32, 4 waves, 4x4 16x16x32 frags per wave, depth-2 pipeline.
// ---------------------------------------------------------------------------
template <int EPI, int OMODE, int A32, int RETR>
__launch_bounds__(256)
__global__ void gemm_bf_k(const void* __restrict__ Av, int lda, int M, int Ka,
                          const u16* __restrict__ Wt,
                          const float* __restrict__ bias,
                          void* __restrict__ Cv, int ldc,
                          const float* __restrict__ o_ex,
                          const float* __restrict__ s_ex,
                          const float* __restrict__ Wex)
{
    constexpr int NBA = A32 ? 2 : 3;
    __shared__ u16 As[NBA * 128 * 32];
    __shared__ u16 Bs[3 * 128 * 32];
    const int row0 = blockIdx.x * 128;
    const int col0 = blockIdx.y * 128;
    const int t    = threadIdx.x;
    const int lane = t & 63;
    const int w    = t >> 6;
    const int wm   = w & 1, wn = w >> 1;

    const int idx0 = t, idx1 = t + 256;
    const u16* Ab = (const u16*)Av;
    const float* Af = (const float*)Av;
    const u16* Ag0 = Ab + (size_t)(row0 + (idx0 >> 2)) * lda + (idx0 & 3) * 8;
    const u16* Ag1 = Ab + (size_t)(row0 + (idx1 >> 2)) * lda + (idx1 & 3) * 8;
    const float* Af0 = Af + (size_t)(row0 + (idx0 >> 2)) * lda + (idx0 & 3) * 8;
    const float* Af1 = Af + (size_t)(row0 + (idx1 >> 2)) * lda + (idx1 & 3) * 8;
    const u16* Bg0 = Wt + (size_t)(col0 + (idx0 >> 2)) * Ka + (idx0 & 3) * 8;
    const u16* Bg1 = Wt + (size_t)(col0 + (idx1 >> 2)) * Ka + (idx1 & 3) * 8;
    const int s0 = idx0 * 8, s1 = idx1 * 8;

    auto stageB = [&](int bi, int kk) {
        u16* bp = Bs + bi * (128 * 32);
        GLDS(Bg0 + kk, bp + s0);
        GLDS(Bg1 + kk, bp + s1);
    };
    auto stageA = [&](int bi, int kk) {
        u16* ap = As + bi * (128 * 32);
        GLDS(Ag0 + kk, ap + s0);
        GLDS(Ag1 + kk, ap + s1);
    };

    float4 P0, P1, P2, P3, Q0, Q1, Q2, Q3;
    auto loadP = [&](int kk) {
        P0 = *(const float4*)(Af0 + kk);     P1 = *(const float4*)(Af0 + kk + 4);
        P2 = *(const float4*)(Af1 + kk);     P3 = *(const float4*)(Af1 + kk + 4);
    };
    auto loadQ = [&](int kk) {
        Q0 = *(const float4*)(Af0 + kk);     Q1 = *(const float4*)(Af0 + kk + 4);
        Q2 = *(const float4*)(Af1 + kk);     Q3 = *(const float4*)(Af1 + kk + 4);
    };
    auto writeP = [&](int bi) {
        u16* ap = As + bi * (128 * 32);
        uint4 u0, u1;
        u0.x = pk2(P0.x, P0.y); u0.y = pk2(P0.z, P0.w);
        u0.z = pk2(P1.x, P1.y); u0.w = pk2(P1.z, P1.w);
        u1.x = pk2(P2.x, P2.y); u1.y = pk2(P2.z, P2.w);
        u1.z = pk2(P3.x, P3.y); u1.w = pk2(P3.z, P3.w);
        *(uint4*)(ap + s0) = u0;
        *(uint4*)(ap + s1) = u1;
    };
    auto writeQ = [&](int bi) {
        u16* ap = As + bi * (128 * 32);
        uint4 u0, u1;
        u0.x = pk2(Q0.x, Q0.y); u0.y = pk2(Q0.z, Q0.w);
        u0.z = pk2(Q1.x, Q1.y); u0.w = pk2(Q1.z, Q1.w);
        u1.x = pk2(Q2.x, Q2.y); u1.y = pk2(Q2.z, Q2.w);
        u1.z = pk2(Q3.x, Q3.y); u1.w = pk2(Q3.z, Q3.w);
        *(uint4*)(ap + s0) = u0;
        *(uint4*)(ap + s1) = u1;
    };

    v4f acc[4][4];
#pragma unroll
    for (int mi = 0; mi < 4; mi++)
#pragma unroll
        for (int ni = 0; ni < 4; ni++) acc[mi][ni] = 0.f;

    const int fr = lane & 15;
    const int fq = (lane >> 4) * 8;
    const int nk = Ka >> 5;

    if (A32) {
        loadP(0);
        stageB(0, 0);
        if (nk > 1) {
            loadQ(32);
            stageB(1, 32);
        }
        writeP(0);
        if (nk > 1) { WAITVL(6); }
        else        { WAITVL(0); }
    } else {
        stageA(0, 0); stageB(0, 0);
        if (nk > 1) { stageA(1, 32); stageB(1, 32); WAITVL(4); }
        else        { WAITVL(0); }
    }
    BAR();

    int rb = 0, sb = 2;
    for (int tI = 0; tI < nk; ++tI) {
        const bool st = (tI + 2) < nk;
        const int kk2 = (tI + 2) << 5;
        if (st) {
            if (A32) {
                if (tI & 1) loadQ(kk2); else loadP(kk2);
                stageB(sb, kk2);
            } else {
                stageA(sb, kk2);
                stageB(sb, kk2);
            }
        }
        const u16* Ar = As + (A32 ? (tI & 1) : rb) * (128 * 32);
        const u16* Br = Bs + rb * (128 * 32);
        v8bf af[4], bv[4];
#pragma unroll
        for (int mi = 0; mi < 4; mi++)
            af[mi] = *(const v8bf*)&Ar[(wm * 64 + mi * 16 + fr) * 32 + fq];
#pragma unroll
        for (int ni = 0; ni < 4; ni++)
            bv[ni] = *(const v8bf*)&Br[(wn * 64 + ni * 16 + fr) * 32 + fq];
#pragma unroll
        for (int mi = 0; mi < 4; mi++)
#pragma unroll
            for (int ni = 0; ni < 4; ni++)
                acc[mi][ni] = __builtin_amdgcn_mfma_f32_16x16x32_bf16(
                    af[mi], bv[ni], acc[mi][ni], 0, 0, 0);

        if (tI + 1 < nk) {
            if (A32) {
                if (tI & 1) writeP((tI + 1) & 1); else writeQ((tI + 1) & 1);
            }
            if (st) { if (A32) { WAITVL(6); } else { WAITVL(4); } }
            else    { WAITVL(0); }
            BAR();
        }
        rb = (rb == 2) ? 0 : rb + 1;
        sb = (sb == 2) ? 0 : sb + 1;
    }

    // D row = quad*4+reg, col = lane&15  [m89-verified]
    const int crow = wm * 64 + (lane >> 4) * 4;
    const int ccol = wn * 64 + (lane & 15);
    float bias_v[4];
#pragma unroll
    for (int ni = 0; ni < 4; ni++) bias_v[ni] = bias[col0 + ccol + ni * 16];

    u16*   Cb = (u16*)Cv;
    float* Cf = (float*)Cv;
#pragma unroll
    for (int mi = 0; mi < 4; mi++) {
#pragma unroll
        for (int reg = 0; reg < 4; reg++) {
            int r = row0 + crow + mi * 16 + reg;
            if (r >= M) continue;
            float ov[8], sv;
            if (RETR) {
#pragma unroll
                for (int u = 0; u < 8; u++) ov[u] = o_ex[(size_t)r * 8 + u];
                sv = s_ex[r];
            }
#pragma unroll
            for (int ni = 0; ni < 4; ni++) {
                int c = col0 + ccol + ni * 16;
                float v = acc[mi][ni][reg] + bias_v[ni];
                if (RETR) {
                    float e = sv * Wex[8 * 256 + c];
#pragma unroll
                    for (int u = 0; u < 8; u++) e = fmaf(ov[u], Wex[u * 256 + c], e);
                    v += e;
                }
                if (EPI == 1) v = fmaxf(v, 0.f);
                if (EPI == 2) v = 1.f / (1.f + expf(-v));
                if (OMODE == 1) Cb[(size_t)r * ldc + c] = f2b(v);
                else            Cf[(size_t)r * ldc + c] = v;
            }
        }
    }
}

// ---------------------------------------------------------------------------
// Fused retrieval megakernel: layer1 (+extras as K-rows) -> hidden in LDS ->
// scores via wqk -> softmax -> V on-the-fly -> ctx.  8 k-groups per block.
// ---------------------------------------------------------------------------
__launch_bounds__(256, 1)
__global__ void retrfuse_k(const float* __restrict__ Zf,      // z_retr [KRR,256]
                           const u16*  __restrict__ W1t,      // wt_rp1 [256][288]
                           const float* __restrict__ b1,      // rp_b1
                           const float* __restrict__ o_ex,    // [KRR,8]
                           const float* __restrict__ s_ex,    // [KRR]
                           const u16*  __restrict__ wqk,      // [>=KKP][1024] bf16
                           const u16*  __restrict__ Wv,       // wt_kv2 [256][256]
                           const float* __restrict__ bv2,     // bias_kv+256
                           u16* __restrict__ ctx)             // [KP][256]
{
    __shared__ __align__(16) u16 Az[128 * 256];   // z tile; later wqk(16K)+Vtiles(32K)
    __shared__ __align__(16) u16 Ax[128 * 32];    // extra K rows (o|s|0), swizzled
    __shared__ __align__(16) u16 Bp[2 * 128 * 32];// B panels (phase A); attL in phase B/C
    __shared__ __align__(16) u16 Hs[128 * 256];   // hidden, XOR-swizzled

    float* attL = (float*)Bp;

    const int bx = blockIdx.x;
    const int row0 = bx * 128;
    const int t = threadIdx.x, lane = t & 63, w = t >> 6;
    const int wm = w & 1, wn = w >> 1;
    const int fr = lane & 15, fq = (lane >> 4) * 8;
    const int idx0 = t, idx1 = t + 256;

    auto stageBt = [&](int tts) {
        int p2 = (tts >= 9) ? 1 : 0;
        int s2 = tts - p2 * 9;
        const u16* g0 = W1t + (size_t)(p2 * 128 + (idx0 >> 2)) * 288 + (idx0 & 3) * 8 + s2 * 32;
        const u16* g1 = W1t + (size_t)(p2 * 128 + (idx1 >> 2)) * 288 + (idx1 & 3) * 8 + s2 * 32;
        u16* bp = Bp + (tts & 1) * (128 * 32);
        GLDS(g0, bp + idx0 * 8);
        GLDS(g1, bp + idx1 * 8);
    };

    // ---- phase A staging: z (swizzled), extras, first B panel ----
    {
        const float* zb = Zf + (size_t)row0 * 256;
        float4 pa[4], pb[4];
#pragma unroll
        for (int j = 0; j < 4; j++) {
            int c = j * 256 + t, r = c >> 5, sl = c & 31;
            const float* g = zb + (size_t)r * 256 + sl * 8;
            pa[j] = *(const float4*)g;
            pb[j] = *(const float4*)(g + 4);
        }
        stageBt(0);
#pragma unroll
        for (int j = 0; j < 16; j++) {
            int c = j * 256 + t, r = c >> 5, sl = c & 31;
            int jr = j & 3;
            uint4 u;
            u.x = pk2(pa[jr].x, pa[jr].y); u.y = pk2(pa[jr].z, pa[jr].w);
            u.z = pk2(pb[jr].x, pb[jr].y); u.w = pk2(pb[jr].z, pb[jr].w);
            *(uint4*)((char*)Az + (size_t)r * 512 + ((sl ^ (r & 7)) * 16)) = u;
            int jn = j + 4;
            if (jn < 16) {
                int cn = jn * 256 + t, rn = cn >> 5, sn = cn & 31;
                const float* gn = zb + (size_t)rn * 256 + sn * 8;
                pa[jr] = *(const float4*)gn;
                pb[jr] = *(const float4*)(gn + 4);
            }
        }
#pragma unroll
        for (int j = 0; j < 2; j++) {
            int c = j * 256 + t, r = c >> 2, sl = c & 3;
            int rg = row0 + r;
            uint4 u = make_uint4(0u, 0u, 0u, 0u);
            if (sl == 0) {
                float4 o0 = *(const float4*)(o_ex + (size_t)rg * 8);
                float4 o1 = *(const float4*)(o_ex + (size_t)rg * 8 + 4);
                u.x = pk2(o0.x, o0.y); u.y = pk2(o0.z, o0.w);
                u.z = pk2(o1.x, o1.y); u.w = pk2(o1.z, o1.w);
            } else if (sl == 1) {
                u.x = pk2(s_ex[rg], 0.f);
            }
            *(uint4*)((char*)Ax + r * 64 + ((sl ^ (r & 3)) * 16)) = u;
        }
        WAITVL(0);
        BAR();
    }

    // ---- phase A: hidden = relu([z|o|s] @ W1 + b1), 2 passes x 9 K-steps ----
    v4f acc[4][4];
#pragma unroll
    for (int mi = 0; mi < 4; mi++)
#pragma unroll
        for (int ni = 0; ni < 4; ni++) acc[mi][ni] = 0.f;

    for (int tt = 0; tt < 18; ++tt) {
        if (tt + 1 < 18) stageBt(tt + 1);
        const int pass = (tt >= 9) ? 1 : 0;
        const int s = tt - pass * 9;
        const u16* Br = Bp + (tt & 1) * (128 * 32);
        v8bf af[4], bb[4];
#pragma unroll
        for (int mi = 0; mi < 4; mi++) {
            int row = wm * 64 + mi * 16 + fr;
            if (s < 8)
                af[mi] = *(const v8bf*)((const char*)Az + (size_t)row * 512 +
                                        (((s * 4 + (fq >> 3)) ^ (row & 7)) * 16));
            else
                af[mi] = *(const v8bf*)((const char*)Ax + row * 64 +
                                        (((fq >> 3) ^ (row & 3)) * 16));
        }
#pragma unroll
        for (int ni = 0; ni < 4; ni++)
            bb[ni] = *(const v8bf*)&Br[(wn * 64 + ni * 16 + fr) * 32 + fq];
#pragma unroll
        for (int mi = 0; mi < 4; mi++)
#pragma unroll
            for (int ni = 0; ni < 4; ni++)
                acc[mi][ni] = __builtin_amdgcn_mfma_f32_16x16x32_bf16(
                    af[mi], bb[ni], acc[mi][ni], 0, 0, 0);

        if (s == 8) {
            const int col0p = pass * 128;
            const int crow = wm * 64 + (lane >> 4) * 4;
            const int ccol = wn * 64 + fr;
            float bvv[4];
#pragma unroll
            for (int ni = 0; ni < 4; ni++) bvv[ni] = b1[col0p + ccol + ni * 16];
#pragma unroll
            for (int mi = 0; mi < 4; mi++)
#pragma unroll
                for (int reg = 0; reg < 4; reg++) {
                    int rl = crow + mi * 16 + reg;
#pragma unroll
                    for (int ni = 0; ni < 4; ni++) {
                        int c = col0p + ccol + ni * 16;
                        float v = fmaxf(acc[mi][ni][reg] + bvv[ni], 0.f);
                        *(u16*)((char*)Hs + (size_t)rl * 512 +
                                (((c >> 3) ^ (rl & 7)) * 16) + (c & 7) * 2) = f2b(v);
                    }
                }
#pragma unroll
            for (int mi = 0; mi < 4; mi++)
#pragma unroll
                for (int ni = 0; ni < 4; ni++) acc[mi][ni] = 0.f;
        }
        if (tt < 17) { WAITVL(0); BAR(); }
    }

    // ---- stage wqk (into Az[0:16K]) + V-tile round 0 (Az[16K:48K]) ----
    auto stageV = [&](int rr) {
#pragma unroll
        for (int j = 0; j < 4; j++) {
            int c = j * 256 + t;
            int tile = c >> 9, cc = c & 511;
            int vr = cc >> 5, sp = cc & 31;
            int nts = tile * 8 + rr;
            const u16* g = Wv + (size_t)(nts * 16 + vr) * 256 + ((sp ^ (vr & 7)) * 8);
            GLDS(g, (u16*)((char*)Az + 16384 + (tile * 2 + (rr & 1)) * 8192 + cc * 16));
        }
    };
#pragma unroll
    for (int j = 0; j < 4; j++) {
        int c = j * 256 + t;
        GLDS(wqk + (size_t)(bx * 8) * 1024 + c * 8, (u16*)((char*)Az + c * 16));
    }
    stageV(0);
    WAITVL(4);   // wqk (4 oldest) done; V-tile 0 stays in flight over phase B
    BAR();

    // ---- phase B: scores + softmax (wave handles 2 k's) ----
#pragma unroll
    for (int kk = 0; kk < 2; kk++) {
        int kloc = w * 2 + kk;
        v4f sc; sc = 0.f;
#pragma unroll
        for (int s = 0; s < 8; s++) {
            int row = kloc * 16 + fr;
            v8bf ha = *(const v8bf*)((const char*)Hs + (size_t)row * 512 +
                                     (((s * 4 + (fq >> 3)) ^ (row & 7)) * 16));
            v4f zf; zf = 0.f;
            v8bf bq = __builtin_bit_cast(v8bf, zf);
            if (fr < 4)
                bq = *(const v8bf*)((const char*)Az + kloc * 2048 + fr * 512 + s * 64 + fq * 2);
            sc = __builtin_amdgcn_mfma_f32_16x16x32_bf16(ha, bq, sc, 0, 0, 0);
        }
        float s0 = sc[0] * 0.125f, s1 = sc[1] * 0.125f;
        float s2 = sc[2] * 0.125f, s3 = sc[3] * 0.125f;
        float mx = fmaxf(fmaxf(s0, s1), fmaxf(s2, s3));
        mx = fmaxf(mx, __shfl_xor(mx, 16));
        mx = fmaxf(mx, __shfl_xor(mx, 32));
        float p0 = __expf(s0 - mx), p1 = __expf(s1 - mx);
        float p2 = __expf(s2 - mx), p3 = __expf(s3 - mx);
        float sm = p0 + p1 + p2 + p3;
        sm += __shfl_xor(sm, 16);
        sm += __shfl_xor(sm, 32);
        float inv = 1.f / sm;
        if (fr < 4) {
            float4 a4 = make_float4(p0 * inv, p1 * inv, p2 * inv, p3 * inv);
            *(float4*)&attL[kloc * 64 + fr * 16 + (lane >> 4) * 4] = a4;
        }
    }
    WAITVL(0);
    BAR();

    // ---- phase C: V on the fly + att-weighted reduction ----
    const int khalf = w & 1, nth = w >> 1;
    v8bf af4[4][8];
#pragma unroll
    for (int kj = 0; kj < 4; kj++) {
        int row = (khalf * 4 + kj) * 16 + fr;
#pragma unroll
        for (int s = 0; s < 8; s++)
            af4[kj][s] = *(const v8bf*)((const char*)Hs + (size_t)row * 512 +
                                        (((s * 4 + (fq >> 3)) ^ (row & 7)) * 16));
    }
    for (int r = 0; r < 8; ++r) {
        if (r < 7) stageV(r + 1);
        int nt = nth * 8 + r;
        const char* cb = (const char*)Az + 16384 + (nth * 2 + (r & 1)) * 8192;
        v8bf bvf[8];
#pragma unroll
        for (int s = 0; s < 8; s++)
            bvf[s] = *(const v8bf*)(cb + fr * 512 + (((s * 4 + (fq >> 3)) ^ (fr & 7)) * 16));
        float bvb = bv2[nt * 16 + fr];
#pragma unroll
        for (int kj = 0; kj < 4; kj++) {
            int kloc = khalf * 4 + kj;
            v4f d; d = 0.f;
#pragma unroll
            for (int s = 0; s < 8; s++)
                d = __builtin_amdgcn_mfma_f32_16x16x32_bf16(af4[kj][s], bvf[s], d, 0, 0, 0);
            float4 av = *(const float4*)&attL[kloc * 64 + (nt >> 2) * 16 + (lane >> 4) * 4];
            float val = av.x * d[0] + av.y * d[1] + av.z * d[2] + av.w * d[3];
            val += __shfl_xor(val, 16);
            val += __shfl_xor(val, 32);
            if (lane < 16)
                ctx[(size_t)(bx * 8 + kloc) * 256 + nt * 16 + lane] = f2b(val + bvb);
        }
        if (r < 7) { WAITVL(4); BAR(); }   // drains stageV (FIFO-oldest); stores may fly
    }
}

// ---------------------------------------------------------------------------
// Weight prep
// ---------------------------------------------------------------------------
__global__ void wtpose_k(const float* __restrict__ W, int ld, int coloff,
                         int fi, int Kpad, u16* __restrict__ Wt)
{
    int g = blockIdx.x * 256 + threadIdx.x;
    if (g >= 256 * Kpad) return;
    int o = g / Kpad, i = g - o * Kpad;
    Wt[g] = f2b(i < fi ? W[(size_t)i * ld + coloff + o] : 0.f);
}

// Fused weight: Wt_out[j*256+i] = sum_m A[i,m] * Binw[m*ldb + off + j]
// Optionally also writes fp32 copy (j-major) to out32.
__global__ void wfuse_k(const float* __restrict__ A, const float* __restrict__ Binw,
                        int ldb, int off, const float* __restrict__ ba,
                        const float* __restrict__ bb,
                        u16* __restrict__ Wt_out, float* __restrict__ bias_out,
                        float* __restrict__ out32)
{
    __shared__ float As[256];
    __shared__ float bs[256];
    int i = blockIdx.x, j = threadIdx.x;
    As[j] = A[(size_t)i * 256 + j];
    bs[j] = ba[j];
    __syncthreads();
    float acc = 0.f, accb = 0.f;
    for (int m = 0; m < 256; m++) {
        float bv = Binw[(size_t)m * ldb + off + j];
        acc = fmaf(As[m], bv, acc);
        if (i == 0) accb = fmaf(bs[m], bv, accb);
    }
    Wt_out[(size_t)j * 256 + i] = f2b(acc);
    if (out32) out32[(size_t)j * 256 + i] = acc;
    if (i == 0) bias_out[j] = bb[j] + accb;
}

// QK-fused weight for wqk GEMM:
// Wt_qk[(h*256+m)*256 + c] = sum_d Qf32[(h*64+d)*256+c] * Wk32[(h*64+d)*256+m]
// bias_qk[h*256+m]         = sum_d bias_qf[h*64+d]      * Wk32[(h*64+d)*256+m]
__global__ void qkfuse_k(const float* __restrict__ Qf32, const float* __restrict__ Wk32,
                         const float* __restrict__ bqf,
                         u16* __restrict__ Wtqk, float* __restrict__ bqk)
{
    __shared__ float wk[64];
    __shared__ float bq[64];
    int b = blockIdx.x;
    int h = b >> 8, m = b & 255;
    int c = threadIdx.x;
    if (c < 64) {
        wk[c] = Wk32[(size_t)(h * 64 + c) * 256 + m];
        bq[c] = bqf[h * 64 + c];
    }
    __syncthreads();
    float acc = 0.f;
    for (int d = 0; d < 64; d++)
        acc = fmaf(Qf32[(size_t)(h * 64 + d) * 256 + c], wk[d], acc);
    Wtqk[(size_t)b * 256 + c] = f2b(acc);
    if (c == 0) {
        float ab = 0.f;
        for (int d = 0; d < 64; d++) ab = fmaf(bq[d], wk[d], ab);
        bqk[b] = ab;
    }
}

__global__ void conv_f2b_k(const float* __restrict__ src, u16* __restrict__ dst, size_t n4)
{
    size_t g = (size_t)blockIdx.x * 256 + threadIdx.x;
    if (g >= n4) return;
    float4 v = ((const float4*)src)[g];
    ((ushort4*)dst)[g] = make_ushort4(f2b(v.x), f2b(v.y), f2b(v.z), f2b(v.w));
}

// gather h_cone[nids] -> acat cols 0..255 (bf16, ld 512)
__global__ void gather_hq_k(const float* __restrict__ hc, const int* __restrict__ nids,
                            u16* __restrict__ acat)
{
    int t = threadIdx.x;
    int k = blockIdx.x * 4 + (t >> 6);
    int c = t & 63;
    if (k >= KKP) return;
    int nid = nids[k];
    float4 v = ((const float4*)hc)[(size_t)nid * 64 + c];
    *(ushort4*)&acat[(size_t)k * 512 + c * 4] =
        make_ushort4(f2b(v.x), f2b(v.y), f2b(v.z), f2b(v.w));
}

// ---------------------------------------------------------------------------
// Scatter (last-write-wins)
// ---------------------------------------------------------------------------
__global__ void winner_k(const int* __restrict__ nids, int* __restrict__ winner)
{
    int gid = blockIdx.x * 256 + threadIdx.x;
    if (gid < KKP) atomicMax(&winner[nids[gid]], gid);
}

__global__ void scatter_h_k(const int* __restrict__ nids, const int* __restrict__ winner,
                            const float* __restrict__ hc, const float* __restrict__ gate,
                            const float* __restrict__ upd, u16* __restrict__ hb)
{
    int t = threadIdx.x;
    int k = blockIdx.x * 4 + (t >> 6);
    int c = t & 63;
    if (k >= KKP) return;
    int nid = nids[k];
    if (winner[nid] != k) return;
    float4 hv = ((const float4*)hc)[(size_t)nid * 64 + c];
    float4 gv = ((const float4*)gate)[(size_t)k * 64 + c];
    float4 uv = ((const float4*)upd)[(size_t)k * 64 + c];
    *(ushort4*)&hb[(size_t)nid * 256 + c * 4] = make_ushort4(
        f2b(hv.x + gv.x * uv.x), f2b(hv.y + gv.y * uv.y),
        f2b(hv.z + gv.z * uv.z), f2b(hv.w + gv.w * uv.w));
}

// ---------------------------------------------------------------------------
// CSR build
// ---------------------------------------------------------------------------
__global__ void edge_count_k(const int* __restrict__ dst, int* __restrict__ cnt, int e)
{
    int gid = blockIdx.x * 256 + threadIdx.x;
    if (gid < e) atomicAdd(&cnt[dst[gid]], 1);
}

__global__ void isd_k(const int* __restrict__ cnt, float* __restrict__ isd, int n)
{
    int gid = blockIdx.x * 256 + threadIdx.x;
    if (gid < n) isd[gid] = rsqrtf((float)(cnt[gid] + 1));
}

#define SCANB 1024
__global__ void scan1_k(const int* __restrict__ in, int* __restrict__ out,
                        int* __restrict__ bsums, int n)
{
    __shared__ int s[SCANB];
    int tid = threadIdx.x;
    int gid = blockIdx.x * SCANB + tid;
    int v = (gid < n) ? in[gid] : 0;
    s[tid] = v;
    __syncthreads();
    for (int off = 1; off < SCANB; off <<= 1) {
        int add = (tid >= off) ? s[tid - off] : 0;
        __syncthreads();
        s[tid] += add;
        __syncthreads();
    }
    if (gid < n) out[gid] = s[tid] - v;
    if (tid == SCANB - 1) bsums[blockIdx.x] = s[tid];
}

__global__ void scan2_k(int* bsums, int nb)
{
    if (threadIdx.x == 0 && blockIdx.x == 0) {
        int run = 0;
        for (int i = 0; i < nb; i++) { int v = bsums[i]; bsums[i] = run; run += v; }
    }
}

__global__ void scan3_k(int* __restrict__ out, const int* __restrict__ bsums, int n, int total)
{
    int gid = blockIdx.x * SCANB + threadIdx.x;
    if (gid < n) out[gid] += bsums[blockIdx.x];
    if (gid == 0) out[n] = total;
}

__global__ void csr_scatter_k(const int* __restrict__ src, const int* __restrict__ dst,
                              const int* __restrict__ row_start, int* __restrict__ cursor,
                              const float* __restrict__ isd,
                              int* __restrict__ csr_src, float* __restrict__ csr_w, int e)
{
    int gid = blockIdx.x * 256 + threadIdx.x;
    if (gid < e) {
        int sP = src[gid], dP = dst[gid];
        int pos = row_start[dP] + atomicAdd(&cursor[dP], 1);
        csr_src[pos] = sP;
        csr_w[pos] = isd[sP] * isd[dP];
    }
}

// GCN aggregation: wave per node, ushort4 per lane
template <int RELU>
__launch_bounds__(256)
__global__ void gnn_agg_k(const u16* __restrict__ x, const int* __restrict__ row_start,
                          const int* __restrict__ csr_src, const float* __restrict__ csr_w,
                          const float* __restrict__ isd, u16* __restrict__ outp)
{
    int node = blockIdx.x * 4 + (threadIdx.x >> 6);
    int lane = threadIdx.x & 63;
    if (node >= NN) return;
    float si = isd[node];
    float sii = si * si;
    ushort4 sv = ((const ushort4*)x)[(size_t)node * 64 + lane];
    float a0 = b2f(sv.x) * sii, a1 = b2f(sv.y) * sii;
    float a2 = b2f(sv.z) * sii, a3 = b2f(sv.w) * sii;
    int s0 = row_start[node], s1 = row_start[node + 1];
    for (int j = s0; j < s1; j++) {
        int sP = csr_src[j];
        float wv = csr_w[j];
        ushort4 v = ((const ushort4*)x)[(size_t)sP * 64 + lane];
        a0 = fmaf(b2f(v.x), wv, a0);
        a1 = fmaf(b2f(v.y), wv, a1);
        a2 = fmaf(b2f(v.z), wv, a2);
        a3 = fmaf(b2f(v.w), wv, a3);
    }
    if (RELU) {
        a0 = fmaxf(a0, 0.f); a1 = fmaxf(a1, 0.f);
        a2 = fmaxf(a2, 0.f); a3 = fmaxf(a3, 0.f);
    }
    ((ushort4*)outp)[(size_t)node * 64 + lane] =
        make_ushort4(f2b(a0), f2b(a1), f2b(a2), f2b(a3));
}

// head layer-2 + teacher add
__launch_bounds__(256)
__global__ void head_out_k(const u16* __restrict__ thid, const float* __restrict__ W2,
                           const float* __restrict__ b2, const float* __restrict__ teacher,
                           float* __restrict__ outp, int n)
{
    __shared__ float ts[32][257];
    __shared__ float w2s[256 * 8];
    int t = threadIdx.x;
    int rbase = blockIdx.x * 32;
    for (int i = t; i < 2048; i += 256) w2s[i] = W2[i];
    for (int i = t; i < 32 * 256; i += 256) {
        int rr = i >> 8, cc = i & 255;
        int gr = rbase + rr;
        ts[rr][cc] = (gr < n) ? b2f(thid[(size_t)gr * 256 + cc]) : 0.f;
    }
    __syncthreads();
    int rr = t >> 3, cc = t & 7;
    int gr = rbase + rr;
    if (gr >= n) return;
    float acc = b2[cc];
    for (int kk = 0; kk < 256; kk++)
        acc = fmaf(ts[rr][kk], w2s[kk * 8 + cc], acc);
    outp[(size_t)gr * 8 + cc] = teacher[(size_t)gr * 8 + cc] + acc;
}

// ---------------------------------------------------------------------------
// Host launcher
// ---------------------------------------------------------------------------
extern "C" void kernel_launch(void* const* d_in, const int* in_sizes, int n_in,
                              void* d_out, int out_size, void* d_ws, size_t ws_size,
                              hipStream_t stream)
{
    (void)in_sizes; (void)n_in; (void)out_size; (void)ws_size;
    const float* h_cone     = (const float*)d_in[0];
    const float* z_retr     = (const float*)d_in[1];
    const float* o_retr     = (const float*)d_in[2];
    const float* retr_score = (const float*)d_in[3];
    const float* teacher    = (const float*)d_in[4];
    const int*   nids       = (const int*)d_in[5];
    const int*   edge       = (const int*)d_in[6];
    const float* rp_W1 = (const float*)d_in[7];   const float* rp_b1 = (const float*)d_in[8];
    const float* rp_W2 = (const float*)d_in[9];   const float* rp_b2 = (const float*)d_in[10];
    const float* qp_W  = (const float*)d_in[11];  const float* qp_b  = (const float*)d_in[12];
    const float* inW   = (const float*)d_in[13];  const float* inB   = (const float*)d_in[14];
    const float* outW  = (const float*)d_in[15];  const float* outB  = (const float*)d_in[16];
    const float* gW1   = (const float*)d_in[17];  const float* gB1   = (const float*)d_in[18];
    const float* gW2   = (const float*)d_in[19];  const float* gB2   = (const float*)d_in[20];
    const float* uW1   = (const float*)d_in[21];  const float* uB1   = (const float*)d_in[22];
    const float* uW2   = (const float*)d_in[23];  const float* uB2   = (const float*)d_in[24];
    const float* gnW1  = (const float*)d_in[25];  const float* gnB1  = (const float*)d_in[26];
    const float* gnW2  = (const float*)d_in[27];  const float* gnB2  = (const float*)d_in[28];
    const float* hW1   = (const float*)d_in[29];  const float* hB1   = (const float*)d_in[30];
    const float* hW2   = (const float*)d_in[31];  const float* hB2   = (const float*)d_in[32];
    float* out = (float*)d_out;

    char* ws = (char*)d_ws;
    size_t off = 0;
    auto alloc = [&](size_t bytes) -> void* {
        void* p = ws + off;
        off = (off + bytes + 255) & ~(size_t)255;
        return p;
    };
    u16* hidden = (u16*)alloc((size_t)KRR * 256 * 2);   // GNN overlay buffers
    u16* ctxb   = (u16*)alloc((size_t)KP * 256 * 2);
    u16* acat   = (u16*)alloc((size_t)KP * 512 * 2);
    u16* ghid   = (u16*)alloc((size_t)KP * 256 * 2);
    float* gate = (float*)alloc((size_t)KP * 256 * 4);
    u16* uhid   = (u16*)alloc((size_t)KP * 256 * 2);
    float* upd  = (float*)alloc((size_t)KP * 256 * 4);
    u16* wqk_g  = (u16*)alloc((size_t)KP * 1024 * 2);
    u16* wt_rp1 = (u16*)alloc(256 * 288 * 2);
    u16* wt_kv  = (u16*)alloc(512 * 256 * 2);
    u16* wt_qf  = (u16*)alloc(256 * 256 * 2);
    u16* wt_o   = (u16*)alloc(256 * 256 * 2);
    u16* wt_g1  = (u16*)alloc(256 * 512 * 2);
    u16* wt_g2  = (u16*)alloc(256 * 256 * 2);
    u16* wt_u1  = (u16*)alloc(256 * 256 * 2);
    u16* wt_u2  = (u16*)alloc(256 * 256 * 2);
    u16* wt_gn1 = (u16*)alloc(256 * 256 * 2);
    u16* wt_gn2 = (u16*)alloc(256 * 256 * 2);
    u16* wt_h1  = (u16*)alloc(256 * 256 * 2);
    u16* wt_qk  = (u16*)alloc(1024 * 256 * 2);
    float* Qf32 = (float*)alloc(256 * 256 * 4);
    float* Wk32 = (float*)alloc(256 * 256 * 4);
    float* bias_kv = (float*)alloc(512 * 4);
    float* bias_qf = (float*)alloc(256 * 4);
    float* bias_qk = (float*)alloc(1024 * 4);
    int*   winner    = (int*)alloc(NN * 4);
    int*   cnt       = (int*)alloc(NN * 4);
    int*   cursor    = (int*)alloc(NN * 4);
    int*   row_start = (int*)alloc((NN + 1) * 4);
    int*   bsums     = (int*)alloc(1024 * 4);
    float* isd       = (float*)alloc(NN * 4);
    int*   csr_src   = (int*)alloc((size_t)EE * 4);
    float* csr_w     = (float*)alloc((size_t)EE * 4);

    // GNN stage overlays hidden: 3 buffers of NP rows
    const size_t NPE = (size_t)NP * 256;
    u16* gZ0 = hidden;            // hb -> x2
    u16* gZ1 = hidden + NPE;      // x1 -> h2
    u16* gZ2 = hidden + 2 * NPE;  // h1 -> thid

    const int* esrc = edge;
    const int* edst = edge + EE;

    auto wtp = [&](const float* W, int ld, int coloff, int fi, int Kpad, u16* Wt) {
        wtpose_k<<<(256 * Kpad + 255) / 256, 256, 0, stream>>>(W, ld, coloff, fi, Kpad, Wt);
    };

    // ---- CSR prep ----
    hipMemsetAsync(cnt, 0, NN * 4, stream);
    hipMemsetAsync(cursor, 0, NN * 4, stream);
    edge_count_k<<<(EE + 255) / 256, 256, 0, stream>>>(edst, cnt, EE);
    isd_k<<<(NN + 255) / 256, 256, 0, stream>>>(cnt, isd, NN);
    int nb = (NN + SCANB - 1) / SCANB;
    scan1_k<<<nb, SCANB, 0, stream>>>(cnt, row_start, bsums, NN);
    scan2_k<<<1, 64, 0, stream>>>(bsums, nb);
    scan3_k<<<nb, SCANB, 0, stream>>>(row_start, bsums, NN, EE);
    csr_scatter_k<<<(EE + 255) / 256, 256, 0, stream>>>(esrc, edst, row_start, cursor, isd,
                                                        csr_src, csr_w, EE);

    // ---- weight prep ----
    wtp(rp_W1, 256, 0, 265, 288, wt_rp1);   // K-extended: z(256) + o(8) + score(1) + pad
    wfuse_k<<<256, 256, 0, stream>>>(rp_W2, inW, 768, 256, rp_b2, inB + 256,
                                     wt_kv, bias_kv, Wk32);
    wfuse_k<<<256, 256, 0, stream>>>(rp_W2, inW, 768, 512, rp_b2, inB + 512,
                                     wt_kv + 256 * 256, bias_kv + 256, nullptr);
    wfuse_k<<<256, 256, 0, stream>>>(qp_W, inW, 768, 0, qp_b, inB,
                                     wt_qf, bias_qf, Qf32);
    qkfuse_k<<<1024, 256, 0, stream>>>(Qf32, Wk32, bias_qf, wt_qk, bias_qk);
    wtp(outW, 256, 0, 256, 256, wt_o);
    wtp(gW1,  256, 0, 512, 512, wt_g1);
    wtp(gW2,  256, 0, 256, 256, wt_g2);
    wtp(uW1,  256, 0, 256, 256, wt_u1);
    wtp(uW2,  256, 0, 256, 256, wt_u2);
    wtp(gnW1, 256, 0, 256, 256, wt_gn1);
    wtp(gnW2, 256, 0, 256, 256, wt_gn2);
    wtp(hW1,  256, 0, 256, 256, wt_h1);
    gather_hq_k<<<(KKP + 3) / 4, 256, 0, stream>>>(h_cone, nids, acat);

    // ---- wqk = hq @ QKfused + bias  (query pushed through Wk; [KKP,1024]) ----
    gemm_bf_k<0, 1, 0, 0><<<dim3((KKP + 127) / 128, 8), 256, 0, stream>>>(
        acat, 512, KKP, 256, wt_qk, bias_qk, wqk_g, 1024, nullptr, nullptr, nullptr);

    // ---- fused retrieval megakernel -> ctx ----
    retrfuse_k<<<KRR / 128, 256, 0, stream>>>(
        z_retr, wt_rp1, rp_b1, o_retr, retr_score,
        wqk_g, wt_kv + 256 * 256, bias_kv + 256, ctxb);

    // ---- out-projection ----
    gemm_bf_k<0, 1, 0, 0><<<dim3((KKP + 127) / 128, 2), 256, 0, stream>>>(
        ctxb, 256, KKP, 256, wt_o, outB, acat + 256, 512, nullptr, nullptr, nullptr);

    // ---- gate / update ----
    gemm_bf_k<1, 1, 0, 0><<<dim3((KKP + 127) / 128, 2), 256, 0, stream>>>(
        acat, 512, KKP, 512, wt_g1, gB1, ghid, 256, nullptr, nullptr, nullptr);
    gemm_bf_k<2, 2, 0, 0><<<dim3((KKP + 127) / 128, 2), 256, 0, stream>>>(
        ghid, 256, KKP, 256, wt_g2, gB2, gate, 256, nullptr, nullptr, nullptr);
    gemm_bf_k<1, 1, 0, 0><<<dim3((KKP + 127) / 128, 2), 256, 0, stream>>>(
        acat + 256, 512, KKP, 256, wt_u1, uB1, uhid, 256, nullptr, nullptr, nullptr);
    gemm_bf_k<0, 2, 0, 0><<<dim3((KKP + 127) / 128, 2), 256, 0, stream>>>(
        uhid, 256, KKP, 256, wt_u2, uB2, upd, 256, nullptr, nullptr, nullptr);

    // ---- scatter into hb (bf16 copy of h_cone, winner rows overwritten) ----
    conv_f2b_k<<<(int)(((size_t)NN * 64 + 255) / 256), 256, 0, stream>>>(
        h_cone, gZ0, (size_t)NN * 64);
    hipMemsetAsync(winner, 0xFF, NN * 4, stream);
    winner_k<<<(KKP + 255) / 256, 256, 0, stream>>>(nids, winner);
    scatter_h_k<<<(KKP + 3) / 4, 256, 0, stream>>>(nids, winner, h_cone, gate, upd, gZ0);

    // ---- cone GNN ----
    gemm_bf_k<0, 1, 0, 0><<<dim3((NN + 127) / 128, 2), 256, 0, stream>>>(
        gZ0, 256, NN, 256, wt_gn1, gnB1, gZ1, 256, nullptr, nullptr, nullptr);       // x1
    gnn_agg_k<1><<<(NN + 3) / 4, 256, 0, stream>>>(gZ1, row_start, csr_src, csr_w, isd, gZ2); // h1
    gemm_bf_k<0, 1, 0, 0><<<dim3((NN + 127) / 128, 2), 256, 0, stream>>>(
        gZ2, 256, NN, 256, wt_gn2, gnB2, gZ0, 256, nullptr, nullptr, nullptr);       // x2
    gnn_agg_k<0><<<(NN + 3) / 4, 256, 0, stream>>>(gZ0, row_start, csr_src, csr_w, isd, gZ1); // h2
    gemm_bf_k<1, 1, 0, 0><<<dim3((NN + 127) / 128, 2), 256, 0, stream>>>(
        gZ1, 256, NN, 256, wt_h1, hB1, gZ2, 256, nullptr, nullptr, nullptr);         // thid
    head_out_k<<<(NN + 31) / 32, 256, 0, stream>>>(gZ2, hW2, hB2, teacher, out, NN);
}

// Round 3
// 1450.942 us; speedup vs baseline: 1.2486x; 1.1098x over previous
//
#include <hip/hip_runtime.h>
#include <cstdint>
#include <cstddef>

typedef unsigned short u16;

// Problem constants
#define NN    100000
#define OUTD  8
#define KKP   20000
#define RR    16
#define EE    800000
#define KRR   (KKP*RR)   // 320000
#define KP    20096      // 157*128
#define NP    100096     // 782*128

typedef __bf16 v8bf __attribute__((ext_vector_type(8)));
typedef float  v4f  __attribute__((ext_vector_type(4)));

__device__ __forceinline__ float b2f(u16 u) {
    union { uint32_t i; float f; } v; v.i = (uint32_t)u << 16; return v.f;
}
__device__ __forceinline__ u16 f2b(float f) {
    union { float f; uint32_t i; } v; v.f = f;
    uint32_t i = v.i;
    return (u16)((i + 0x7fffu + ((i >> 16) & 1u)) >> 16);
}
__device__ __forceinline__ uint32_t pk2(float a, float b) {
    return (uint32_t)f2b(a) | ((uint32_t)f2b(b) << 16);
}

#define GLDS(g, l) __builtin_amdgcn_global_load_lds(                         \
    (const __attribute__((address_space(1))) void*)(g),                      \
    (__attribute__((address_space(3))) void*)(l), 16, 0, 0)

#define WAITVL(n) asm volatile("s_waitcnt vmcnt(" #n ") lgkmcnt(0)" ::: "memory")
#define BAR() __builtin_amdgcn_s_barrier()

// ---------------------------------------------------------------------------
// bf16 MFMA GEMM: C[M,Nout] = act(A[M,Ka] @ Wt[Nout,Ka]^T + bias)
// 128x128 tile, BK=32, 4 waves, 4x4 16x16x32 frags per wave, depth-2 pipeline.
// ---------------------------------------------------------------------------
template <int EPI, int OMODE, int A32, int RETR>
__launch_bounds__(256)
__global__ void gemm_bf_k(const void* __restrict__ Av, int lda, int M, int Ka,
                          const u16* __restrict__ Wt,
                          const float* __restrict__ bias,
                          void* __restrict__ Cv, int ldc,
                          const float* __restrict__ o_ex,
                          const float* __restrict__ s_ex,
                          const float* __restrict__ Wex)
{
    constexpr int NBA = A32 ? 2 : 3;
    __shared__ u16 As[NBA * 128 * 32];
    __shared__ u16 Bs[3 * 128 * 32];
    const int row0 = blockIdx.x * 128;
    const int col0 = blockIdx.y * 128;
    const int t    = threadIdx.x;
    const int lane = t & 63;
    const int w    = t >> 6;
    const int wm   = w & 1, wn = w >> 1;

    const int idx0 = t, idx1 = t + 256;
    const u16* Ab = (const u16*)Av;
    const float* Af = (const float*)Av;
    const u16* Ag0 = Ab + (size_t)(row0 + (idx0 >> 2)) * lda + (idx0 & 3) * 8;
    const u16* Ag1 = Ab + (size_t)(row0 + (idx1 >> 2)) * lda + (idx1 & 3) * 8;
    const float* Af0 = Af + (size_t)(row0 + (idx0 >> 2)) * lda + (idx0 & 3) * 8;
    const float* Af1 = Af + (size_t)(row0 + (idx1 >> 2)) * lda + (idx1 & 3) * 8;
    const u16* Bg0 = Wt + (size_t)(col0 + (idx0 >> 2)) * Ka + (idx0 & 3) * 8;
    const u16* Bg1 = Wt + (size_t)(col0 + (idx1 >> 2)) * Ka + (idx1 & 3) * 8;
    const int s0 = idx0 * 8, s1 = idx1 * 8;

    auto stageB = [&](int bi, int kk) {
        u16* bp = Bs + bi * (128 * 32);
        GLDS(Bg0 + kk, bp + s0);
        GLDS(Bg1 + kk, bp + s1);
    };
    auto stageA = [&](int bi, int kk) {
        u16* ap = As + bi * (128 * 32);
        GLDS(Ag0 + kk, ap + s0);
        GLDS(Ag1 + kk, ap + s1);
    };

    float4 P0, P1, P2, P3, Q0, Q1, Q2, Q3;
    auto loadP = [&](int kk) {
        P0 = *(const float4*)(Af0 + kk);     P1 = *(const float4*)(Af0 + kk + 4);
        P2 = *(const float4*)(Af1 + kk);     P3 = *(const float4*)(Af1 + kk + 4);
    };
    auto loadQ = [&](int kk) {
        Q0 = *(const float4*)(Af0 + kk);     Q1 = *(const float4*)(Af0 + kk + 4);
        Q2 = *(const float4*)(Af1 + kk);     Q3 = *(const float4*)(Af1 + kk + 4);
    };
    auto writeP = [&](int bi) {
        u16* ap = As + bi * (128 * 32);
        uint4 u0, u1;
        u0.x = pk2(P0.x, P0.y); u0.y = pk2(P0.z, P0.w);
        u0.z = pk2(P1.x, P1.y); u0.w = pk2(P1.z, P1.w);
        u1.x = pk2(P2.x, P2.y); u1.y = pk2(P2.z, P2.w);
        u1.z = pk2(P3.x, P3.y); u1.w = pk2(P3.z, P3.w);
        *(uint4*)(ap + s0) = u0;
        *(uint4*)(ap + s1) = u1;
    };
    auto writeQ = [&](int bi) {
        u16* ap = As + bi * (128 * 32);
        uint4 u0, u1;
        u0.x = pk2(Q0.x, Q0.y); u0.y = pk2(Q0.z, Q0.w);
        u0.z = pk2(Q1.x, Q1.y); u0.w = pk2(Q1.z, Q1.w);
        u1.x = pk2(Q2.x, Q2.y); u1.y = pk2(Q2.z, Q2.w);
        u1.z = pk2(Q3.x, Q3.y); u1.w = pk2(Q3.z, Q3.w);
        *(uint4*)(ap + s0) = u0;
        *(uint4*)(ap + s1) = u1;
    };

    v4f acc[4][4];
#pragma unroll
    for (int mi = 0; mi < 4; mi++)
#pragma unroll
        for (int ni = 0; ni < 4; ni++) acc[mi][ni] = 0.f;

    const int fr = lane & 15;
    const int fq = (lane >> 4) * 8;
    const int nk = Ka >> 5;

    if (A32) {
        loadP(0);
        stageB(0, 0);
        if (nk > 1) {
            loadQ(32);
            stageB(1, 32);
        }
        writeP(0);
        if (nk > 1) { WAITVL(6); }
        else        { WAITVL(0); }
    } else {
        stageA(0, 0); stageB(0, 0);
        if (nk > 1) { stageA(1, 32); stageB(1, 32); WAITVL(4); }
        else        { WAITVL(0); }
    }
    BAR();

    int rb = 0, sb = 2;
    for (int tI = 0; tI < nk; ++tI) {
        const bool st = (tI + 2) < nk;
        const int kk2 = (tI + 2) << 5;
        if (st) {
            if (A32) {
                if (tI & 1) loadQ(kk2); else loadP(kk2);
                stageB(sb, kk2);
            } else {
                stageA(sb, kk2);
                stageB(sb, kk2);
            }
        }
        const u16* Ar = As + (A32 ? (tI & 1) : rb) * (128 * 32);
        const u16* Br = Bs + rb * (128 * 32);
        v8bf af[4], bv[4];
#pragma unroll
        for (int mi = 0; mi < 4; mi++)
            af[mi] = *(const v8bf*)&Ar[(wm * 64 + mi * 16 + fr) * 32 + fq];
#pragma unroll
        for (int ni = 0; ni < 4; ni++)
            bv[ni] = *(const v8bf*)&Br[(wn * 64 + ni * 16 + fr) * 32 + fq];
#pragma unroll
        for (int mi = 0; mi < 4; mi++)
#pragma unroll
            for (int ni = 0; ni < 4; ni++)
                acc[mi][ni] = __builtin_amdgcn_mfma_f32_16x16x32_bf16(
                    af[mi], bv[ni], acc[mi][ni], 0, 0, 0);

        if (tI + 1 < nk) {
            if (A32) {
                if (tI & 1) writeP((tI + 1) & 1); else writeQ((tI + 1) & 1);
            }
            if (st) { if (A32) { WAITVL(6); } else { WAITVL(4); } }
            else    { WAITVL(0); }
            BAR();
        }
        rb = (rb == 2) ? 0 : rb + 1;
        sb = (sb == 2) ? 0 : sb + 1;
    }

    // D row = quad*4+reg, col = lane&15  [m89-verified]
    const int crow = wm * 64 + (lane >> 4) * 4;
    const int ccol = wn * 64 + (lane & 15);
    float bias_v[4];
#pragma unroll
    for (int ni = 0; ni < 4; ni++) bias_v[ni] = bias[col0 + ccol + ni * 16];

    u16*   Cb = (u16*)Cv;
    float* Cf = (float*)Cv;
#pragma unroll
    for (int mi = 0; mi < 4; mi++) {
#pragma unroll
        for (int reg = 0; reg < 4; reg++) {
            int r = row0 + crow + mi * 16 + reg;
            if (r >= M) continue;
            float ov[8], sv;
            if (RETR) {
#pragma unroll
                for (int u = 0; u < 8; u++) ov[u] = o_ex[(size_t)r * 8 + u];
                sv = s_ex[r];
            }
#pragma unroll
            for (int ni = 0; ni < 4; ni++) {
                int c = col0 + ccol + ni * 16;
                float v = acc[mi][ni][reg] + bias_v[ni];
                if (RETR) {
                    float e = sv * Wex[8 * 256 + c];
#pragma unroll
                    for (int u = 0; u < 8; u++) e = fmaf(ov[u], Wex[u * 256 + c], e);
                    v += e;
                }
                if (EPI == 1) v = fmaxf(v, 0.f);
                if (EPI == 2) v = 1.f / (1.f + expf(-v));
                if (OMODE == 1) Cb[(size_t)r * ldc + c] = f2b(v);
                else            Cf[(size_t)r * ldc + c] = v;
            }
        }
    }
}

// ---------------------------------------------------------------------------
// Fused retrieval megakernel (512 thr / 8 waves, 1 block/CU):
// phase A: hidden = relu([z|o|s] @ W1 + b1) in ONE column pass (B from global
//          regs, depth-2 prefetch, no barriers in K-loop)
// phase B: scores via wqk (LDS) + softmax, 1 k-group per wave
// phase C: V on-the-fly (GLDS, double-buffered) + att-contraction -> ctx
// ---------------------------------------------------------------------------
__launch_bounds__(512, 1)
__global__ void retrfuse_k(const float* __restrict__ Zf,      // z_retr [KRR,256]
                           const u16*  __restrict__ W1t,      // wt_rp1 [256][288]
                           const float* __restrict__ b1,      // rp_b1
                           const float* __restrict__ o_ex,    // [KRR,8]
                           const float* __restrict__ s_ex,    // [KRR]
                           const u16*  __restrict__ wqk,      // [>=KKP][1024] bf16
                           const u16*  __restrict__ Wv,       // wt_kv2 [256][256]
                           const float* __restrict__ bv2,     // bias_kv+256
                           u16* __restrict__ ctx)             // [KP][256]
{
    __shared__ __align__(16) char L[155648];
    char* AZ = L;              // 64KB: z tile (phase A) / V tiles (phase C)
    char* AX = L + 65536;      //  8KB: extra K rows (o|s|0), swizzled
    char* WQ = L + 73728;      // 16KB: wqk; attL overlays own kloc slot
    char* HS = L + 90112;      // 64KB: hidden, XOR-swizzled

    const int bx = blockIdx.x;
    const int row0 = bx * 128;
    const int t = threadIdx.x, lane = t & 63, w = t >> 6;
    const int wm = w & 1, wn = w >> 1;           // 2 x 4 wave grid (phase A)
    const int fr = lane & 15, fq = (lane >> 4) * 8;

    auto stageV = [&](int rr) {
#pragma unroll
        for (int j = 0; j < 4; j++) {
            int c = j * 512 + t;
            int tile = c >> 9, cc = c & 511;
            int vr = cc >> 5, sp = cc & 31;
            int nts = tile * 4 + rr;
            const u16* g = Wv + (size_t)(nts * 16 + vr) * 256 + ((sp ^ (vr & 7)) * 8);
            GLDS(g, (u16*)(AZ + (tile * 2 + (rr & 1)) * 8192 + cc * 16));
        }
    };

    // ---- staging: wqk (GLDS) + z (reg convert, swizzled) + extras ----
    {
        GLDS(wqk + (size_t)(bx * 8) * 1024 + t * 8,         (u16*)(WQ + t * 16));
        GLDS(wqk + (size_t)(bx * 8) * 1024 + (t + 512) * 8, (u16*)(WQ + 8192 + t * 16));
        const float* zb = Zf + (size_t)row0 * 256;
        float4 pa[8], pb[8];
#pragma unroll
        for (int j = 0; j < 8; j++) {
            int c = j * 512 + t, r = c >> 5, sl = c & 31;
            const float* g = zb + (size_t)r * 256 + sl * 8;
            pa[j] = *(const float4*)g;
            pb[j] = *(const float4*)(g + 4);
        }
        {
            int r = t >> 2, sl = t & 3;
            int rg = row0 + r;
            uint4 u = make_uint4(0u, 0u, 0u, 0u);
            if (sl == 0) {
                float4 o0 = *(const float4*)(o_ex + (size_t)rg * 8);
                float4 o1 = *(const float4*)(o_ex + (size_t)rg * 8 + 4);
                u.x = pk2(o0.x, o0.y); u.y = pk2(o0.z, o0.w);
                u.z = pk2(o1.x, o1.y); u.w = pk2(o1.z, o1.w);
            } else if (sl == 1) {
                u.x = pk2(s_ex[rg], 0.f);
            }
            *(uint4*)(AX + r * 64 + ((sl ^ (r & 3)) * 16)) = u;
        }
#pragma unroll
        for (int j = 0; j < 8; j++) {
            int c = j * 512 + t, r = c >> 5, sl = c & 31;
            uint4 u;
            u.x = pk2(pa[j].x, pa[j].y); u.y = pk2(pa[j].z, pa[j].w);
            u.z = pk2(pb[j].x, pb[j].y); u.w = pk2(pb[j].z, pb[j].w);
            *(uint4*)(AZ + (size_t)r * 512 + ((sl ^ (r & 7)) * 16)) = u;
        }
        WAITVL(0);
        BAR();
    }

    // ---- phase A: 9 K-steps, B global->reg depth-2 prefetch, no barriers ----
    v4f acc[4][4];
#pragma unroll
    for (int mi = 0; mi < 4; mi++)
#pragma unroll
        for (int ni = 0; ni < 4; ni++) acc[mi][ni] = 0.f;

    const u16* bp0 = W1t + (size_t)(wn * 64 +  0 + fr) * 288 + fq;
    const u16* bp1 = W1t + (size_t)(wn * 64 + 16 + fr) * 288 + fq;
    const u16* bp2 = W1t + (size_t)(wn * 64 + 32 + fr) * 288 + fq;
    const u16* bp3 = W1t + (size_t)(wn * 64 + 48 + fr) * 288 + fq;

    v8bf bst[3][4];
#define LDB(st, s) { bst[st][0] = *(const v8bf*)(bp0 + (s) * 32); \
                     bst[st][1] = *(const v8bf*)(bp1 + (s) * 32); \
                     bst[st][2] = *(const v8bf*)(bp2 + (s) * 32); \
                     bst[st][3] = *(const v8bf*)(bp3 + (s) * 32); }
    LDB(0, 0)
    LDB(1, 1)
#pragma unroll
    for (int s = 0; s < 9; s++) {
        if (s + 2 < 9) LDB((s + 2) % 3, s + 2)
        v8bf af[4];
#pragma unroll
        for (int mi = 0; mi < 4; mi++) {
            int row = wm * 64 + mi * 16 + fr;
            if (s < 8)
                af[mi] = *(const v8bf*)(AZ + (size_t)row * 512 +
                                        (((s * 4 + (fq >> 3)) ^ (row & 7)) * 16));
            else
                af[mi] = *(const v8bf*)(AX + row * 64 +
                                        (((fq >> 3) ^ (row & 3)) * 16));
        }
#pragma unroll
        for (int mi = 0; mi < 4; mi++)
#pragma unroll
            for (int ni = 0; ni < 4; ni++)
                acc[mi][ni] = __builtin_amdgcn_mfma_f32_16x16x32_bf16(
                    af[mi], bst[s % 3][ni], acc[mi][ni], 0, 0, 0);
    }
#undef LDB

    // ---- phase A epilogue: relu + bias -> Hs (swizzled) ----
    {
        const int crow = wm * 64 + (lane >> 4) * 4;
        float bvv[4];
#pragma unroll
        for (int ni = 0; ni < 4; ni++) bvv[ni] = b1[wn * 64 + fr + ni * 16];
#pragma unroll
        for (int mi = 0; mi < 4; mi++)
#pragma unroll
            for (int reg = 0; reg < 4; reg++) {
                int rl = crow + mi * 16 + reg;
#pragma unroll
                for (int ni = 0; ni < 4; ni++) {
                    int c = wn * 64 + ni * 16 + fr;
                    float v = fmaxf(acc[mi][ni][reg] + bvv[ni], 0.f);
                    *(u16*)(HS + (size_t)rl * 512 +
                            (((c >> 3) ^ (rl & 7)) * 16) + (c & 7) * 2) = f2b(v);
                }
            }
        WAITVL(0);
        BAR();
    }

    // ---- phase B: scores + softmax (wave w -> kloc w); V round 0 prefetch ----
    {
        stageV(0);
        const int kloc = w;
        v4f sc; sc = 0.f;
#pragma unroll
        for (int s = 0; s < 8; s++) {
            int row = kloc * 16 + fr;
            v8bf ha = *(const v8bf*)(HS + (size_t)row * 512 +
                                     (((s * 4 + (fq >> 3)) ^ (row & 7)) * 16));
            v4f zf; zf = 0.f;
            v8bf bq = __builtin_bit_cast(v8bf, zf);
            if (fr < 4)
                bq = *(const v8bf*)(WQ + kloc * 2048 + fr * 512 + s * 64 + fq * 2);
            sc = __builtin_amdgcn_mfma_f32_16x16x32_bf16(ha, bq, sc, 0, 0, 0);
        }
        float s0 = sc[0] * 0.125f, s1 = sc[1] * 0.125f;
        float s2 = sc[2] * 0.125f, s3 = sc[3] * 0.125f;
        float mx = fmaxf(fmaxf(s0, s1), fmaxf(s2, s3));
        mx = fmaxf(mx, __shfl_xor(mx, 16));
        mx = fmaxf(mx, __shfl_xor(mx, 32));
        float p0 = __expf(s0 - mx), p1 = __expf(s1 - mx);
        float p2 = __expf(s2 - mx), p3 = __expf(s3 - mx);
        float sm = p0 + p1 + p2 + p3;
        sm += __shfl_xor(sm, 16);
        sm += __shfl_xor(sm, 32);
        float inv = 1.f / sm;
        if (fr < 4) {
            // attL overlays this wave's own (dead) wqk slot: [head fr][nb]
            float4 a4 = make_float4(p0 * inv, p1 * inv, p2 * inv, p3 * inv);
            *(float4*)(WQ + kloc * 2048 + fr * 64 + (lane >> 4) * 16) = a4;
        }
        WAITVL(0);
        BAR();
    }

    // ---- phase C: V on the fly + att-weighted reduction ----
    {
        const int khalf = w & 1, nth = w >> 1;
        float bvbs[4];
#pragma unroll
        for (int r = 0; r < 4; r++) bvbs[r] = bv2[(nth * 4 + r) * 16 + fr];
        v8bf af4[4][8];
#pragma unroll
        for (int kj = 0; kj < 4; kj++) {
            int row = (khalf * 4 + kj) * 16 + fr;
#pragma unroll
            for (int s = 0; s < 8; s++)
                af4[kj][s] = *(const v8bf*)(HS + (size_t)row * 512 +
                                            (((s * 4 + (fq >> 3)) ^ (row & 7)) * 16));
        }
#pragma unroll
        for (int r = 0; r < 4; ++r) {
            if (r < 3) stageV(r + 1);
            int nt = nth * 4 + r;
            const char* cb = AZ + (nth * 2 + (r & 1)) * 8192;
            v8bf bvf[8];
#pragma unroll
            for (int s = 0; s < 8; s++)
                bvf[s] = *(const v8bf*)(cb + fr * 512 +
                                        (((s * 4 + (fq >> 3)) ^ (fr & 7)) * 16));
#pragma unroll
            for (int kj = 0; kj < 4; kj++) {
                int kloc = khalf * 4 + kj;
                v4f d; d = 0.f;
#pragma unroll
                for (int s = 0; s < 8; s++)
                    d = __builtin_amdgcn_mfma_f32_16x16x32_bf16(af4[kj][s], bvf[s], d, 0, 0, 0);
                float4 av = *(const float4*)(WQ + kloc * 2048 + nth * 64 + (lane >> 4) * 16);
                float val = av.x * d[0] + av.y * d[1] + av.z * d[2] + av.w * d[3];
                val += __shfl_xor(val, 16);
                val += __shfl_xor(val, 32);
                if (lane < 16)
                    ctx[(size_t)(bx * 8 + kloc) * 256 + nt * 16 + lane] = f2b(val + bvbs[r]);
            }
            if (r < 3) { WAITVL(4); BAR(); }   // drains stageV(r+1) (FIFO-oldest); stores fly
        }
    }
}

// ---------------------------------------------------------------------------
// Weight prep
// ---------------------------------------------------------------------------
__global__ void wtpose_k(const float* __restrict__ W, int ld, int coloff,
                         int fi, int Kpad, u16* __restrict__ Wt)
{
    int g = blockIdx.x * 256 + threadIdx.x;
    if (g >= 256 * Kpad) return;
    int o = g / Kpad, i = g - o * Kpad;
    Wt[g] = f2b(i < fi ? W[(size_t)i * ld + coloff + o] : 0.f);
}

// Fused weight: Wt_out[j*256+i] = sum_m A[i,m] * Binw[m*ldb + off + j]
// Optionally also writes fp32 copy (j-major) to out32.
__global__ void wfuse_k(const float* __restrict__ A, const float* __restrict__ Binw,
                        int ldb, int off, const float* __restrict__ ba,
                        const float* __restrict__ bb,
                        u16* __restrict__ Wt_out, float* __restrict__ bias_out,
                        float* __restrict__ out32)
{
    __shared__ float As[256];
    __shared__ float bs[256];
    int i = blockIdx.x, j = threadIdx.x;
    As[j] = A[(size_t)i * 256 + j];
    bs[j] = ba[j];
    __syncthreads();
    float acc = 0.f, accb = 0.f;
    for (int m = 0; m < 256; m++) {
        float bv = Binw[(size_t)m * ldb + off + j];
        acc = fmaf(As[m], bv, acc);
        if (i == 0) accb = fmaf(bs[m], bv, accb);
    }
    Wt_out[(size_t)j * 256 + i] = f2b(acc);
    if (out32) out32[(size_t)j * 256 + i] = acc;
    if (i == 0) bias_out[j] = bb[j] + accb;
}

// QK-fused weight for wqk GEMM:
// Wt_qk[(h*256+m)*256 + c] = sum_d Qf32[(h*64+d)*256+c] * Wk32[(h*64+d)*256+m]
// bias_qk[h*256+m]         = sum_d bias_qf[h*64+d]      * Wk32[(h*64+d)*256+m]
__global__ void qkfuse_k(const float* __restrict__ Qf32, const float* __restrict__ Wk32,
                         const float* __restrict__ bqf,
                         u16* __restrict__ Wtqk, float* __restrict__ bqk)
{
    __shared__ float wk[64];
    __shared__ float bq[64];
    int b = blockIdx.x;
    int h = b >> 8, m = b & 255;
    int c = threadIdx.x;
    if (c < 64) {
        wk[c] = Wk32[(size_t)(h * 64 + c) * 256 + m];
        bq[c] = bqf[h * 64 + c];
    }
    __syncthreads();
    float acc = 0.f;
    for (int d = 0; d < 64; d++)
        acc = fmaf(Qf32[(size_t)(h * 64 + d) * 256 + c], wk[d], acc);
    Wtqk[(size_t)b * 256 + c] = f2b(acc);
    if (c == 0) {
        float ab = 0.f;
        for (int d = 0; d < 64; d++) ab = fmaf(bq[d], wk[d], ab);
        bqk[b] = ab;
    }
}

__global__ void conv_f2b_k(const float* __restrict__ src, u16* __restrict__ dst, size_t n4)
{
    size_t g = (size_t)blockIdx.x * 256 + threadIdx.x;
    if (g >= n4) return;
    float4 v = ((const float4*)src)[g];
    ((ushort4*)dst)[g] = make_ushort4(f2b(v.x), f2b(v.y), f2b(v.z), f2b(v.w));
}

// gather h_cone[nids] -> acat cols 0..255 (bf16, ld 512)
__global__ void gather_hq_k(const float* __restrict__ hc, const int* __restrict__ nids,
                            u16* __restrict__ acat)
{
    int t = threadIdx.x;
    int k = blockIdx.x * 4 + (t >> 6);
    int c = t & 63;
    if (k >= KKP) return;
    int nid = nids[k];
    float4 v = ((const float4*)hc)[(size_t)nid * 64 + c];
    *(ushort4*)&acat[(size_t)k * 512 + c * 4] =
        make_ushort4(f2b(v.x), f2b(v.y), f2b(v.z), f2b(v.w));
}

// ---------------------------------------------------------------------------
// Scatter (last-write-wins)
// ---------------------------------------------------------------------------
__global__ void winner_k(const int* __restrict__ nids, int* __restrict__ winner)
{
    int gid = blockIdx.x * 256 + threadIdx.x;
    if (gid < KKP) atomicMax(&winner[nids[gid]], gid);
}

__global__ void scatter_h_k(const int* __restrict__ nids, const int* __restrict__ winner,
                            const float* __restrict__ hc, const float* __restrict__ gate,
                            const float* __restrict__ upd, u16* __restrict__ hb)
{
    int t = threadIdx.x;
    int k = blockIdx.x * 4 + (t >> 6);
    int c = t & 63;
    if (k >= KKP) return;
    int nid = nids[k];
    if (winner[nid] != k) return;
    float4 hv = ((const float4*)hc)[(size_t)nid * 64 + c];
    float4 gv = ((const float4*)gate)[(size_t)k * 64 + c];
    float4 uv = ((const float4*)upd)[(size_t)k * 64 + c];
    *(ushort4*)&hb[(size_t)nid * 256 + c * 4] = make_ushort4(
        f2b(hv.x + gv.x * uv.x), f2b(hv.y + gv.y * uv.y),
        f2b(hv.z + gv.z * uv.z), f2b(hv.w + gv.w * uv.w));
}

// ---------------------------------------------------------------------------
// CSR build
// ---------------------------------------------------------------------------
__global__ void edge_count_k(const int* __restrict__ dst, int* __restrict__ cnt, int e)
{
    int gid = blockIdx.x * 256 + threadIdx.x;
    if (gid < e) atomicAdd(&cnt[dst[gid]], 1);
}

__global__ void isd_k(const int* __restrict__ cnt, float* __restrict__ isd, int n)
{
    int gid = blockIdx.x * 256 + threadIdx.x;
    if (gid < n) isd[gid] = rsqrtf((float)(cnt[gid] + 1));
}

#define SCANB 1024
__global__ void scan1_k(const int* __restrict__ in, int* __restrict__ out,
                        int* __restrict__ bsums, int n)
{
    __shared__ int s[SCANB];
    int tid = threadIdx.x;
    int gid = blockIdx.x * SCANB + tid;
    int v = (gid < n) ? in[gid] : 0;
    s[tid] = v;
    __syncthreads();
    for (int off = 1; off < SCANB; off <<= 1) {
        int add = (tid >= off) ? s[tid - off] : 0;
        __syncthreads();
        s[tid] += add;
        __syncthreads();
    }
    if (gid < n) out[gid] = s[tid] - v;
    if (tid == SCANB - 1) bsums[blockIdx.x] = s[tid];
}

__global__ void scan2_k(int* bsums, int nb)
{
    if (threadIdx.x == 0 && blockIdx.x == 0) {
        int run = 0;
        for (int i = 0; i < nb; i++) { int v = bsums[i]; bsums[i] = run; run += v; }
    }
}

__global__ void scan3_k(int* __restrict__ out, const int* __restrict__ bsums, int n, int total)
{
    int gid = blockIdx.x * SCANB + threadIdx.x;
    if (gid < n) out[gid] += bsums[blockIdx.x];
    if (gid == 0) out[n] = total;
}

__global__ void csr_scatter_k(const int* __restrict__ src, const int* __restrict__ dst,
                              const int* __restrict__ row_start, int* __restrict__ cursor,
                              const float* __restrict__ isd,
                              int* __restrict__ csr_src, float* __restrict__ csr_w, int e)
{
    int gid = blockIdx.x * 256 + threadIdx.x;
    if (gid < e) {
        int sP = src[gid], dP = dst[gid];
        int pos = row_start[dP] + atomicAdd(&cursor[dP], 1);
        csr_src[pos] = sP;
        csr_w[pos] = isd[sP] * isd[dP];
    }
}

// GCN aggregation: wave per node, ushort4 per lane
template <int RELU>
__launch_bounds__(256)
__global__ void gnn_agg_k(const u16* __restrict__ x, const int* __restrict__ row_start,
                          const int* __restrict__ csr_src, const float* __restrict__ csr_w,
                          const float* __restrict__ isd, u16* __restrict__ outp)
{
    int node = blockIdx.x * 4 + (threadIdx.x >> 6);
    int lane = threadIdx.x & 63;
    if (node >= NN) return;
    float si = isd[node];
    float sii = si * si;
    ushort4 sv = ((const ushort4*)x)[(size_t)node * 64 + lane];
    float a0 = b2f(sv.x) * sii, a1 = b2f(sv.y) * sii;
    float a2 = b2f(sv.z) * sii, a3 = b2f(sv.w) * sii;
    int s0 = row_start[node], s1 = row_start[node + 1];
    for (int j = s0; j < s1; j++) {
        int sP = csr_src[j];
        float wv = csr_w[j];
        ushort4 v = ((const ushort4*)x)[(size_t)sP * 64 + lane];
        a0 = fmaf(b2f(v.x), wv, a0);
        a1 = fmaf(b2f(v.y), wv, a1);
        a2 = fmaf(b2f(v.z), wv, a2);
        a3 = fmaf(b2f(v.w), wv, a3);
    }
    if (RELU) {
        a0 = fmaxf(a0, 0.f); a1 = fmaxf(a1, 0.f);
        a2 = fmaxf(a2, 0.f); a3 = fmaxf(a3, 0.f);
    }
    ((ushort4*)outp)[(size_t)node * 64 + lane] =
        make_ushort4(f2b(a0), f2b(a1), f2b(a2), f2b(a3));
}

// head layer-2 + teacher add
__launch_bounds__(256)
__global__ void head_out_k(const u16* __restrict__ thid, const float* __restrict__ W2,
                           const float* __restrict__ b2, const float* __restrict__ teacher,
                           float* __restrict__ outp, int n)
{
    __shared__ float ts[32][257];
    __shared__ float w2s[256 * 8];
    int t = threadIdx.x;
    int rbase = blockIdx.x * 32;
    for (int i = t; i < 2048; i += 256) w2s[i] = W2[i];
    for (int i = t; i < 32 * 256; i += 256) {
        int rr = i >> 8, cc = i & 255;
        int gr = rbase + rr;
        ts[rr][cc] = (gr < n) ? b2f(thid[(size_t)gr * 256 + cc]) : 0.f;
    }
    __syncthreads();
    int rr = t >> 3, cc = t & 7;
    int gr = rbase + rr;
    if (gr >= n) return;
    float acc = b2[cc];
    for (int kk = 0; kk < 256; kk++)
        acc = fmaf(ts[rr][kk], w2s[kk * 8 + cc], acc);
    outp[(size_t)gr * 8 + cc] = teacher[(size_t)gr * 8 + cc] + acc;
}

// ---------------------------------------------------------------------------
// Host launcher
// ---------------------------------------------------------------------------
extern "C" void kernel_launch(void* const* d_in, const int* in_sizes, int n_in,
                              void* d_out, int out_size, void* d_ws, size_t ws_size,
                              hipStream_t stream)
{
    (void)in_sizes; (void)n_in; (void)out_size; (void)ws_size;
    const float* h_cone     = (const float*)d_in[0];
    const float* z_retr     = (const float*)d_in[1];
    const float* o_retr     = (const float*)d_in[2];
    const float* retr_score = (const float*)d_in[3];
    const float* teacher    = (const float*)d_in[4];
    const int*   nids       = (const int*)d_in[5];
    const int*   edge       = (const int*)d_in[6];
    const float* rp_W1 = (const float*)d_in[7];   const float* rp_b1 = (const float*)d_in[8];
    const float* rp_W2 = (const float*)d_in[9];   const float* rp_b2 = (const float*)d_in[10];
    const float* qp_W  = (const float*)d_in[11];  const float* qp_b  = (const float*)d_in[12];
    const float* inW   = (const float*)d_in[13];  const float* inB   = (const float*)d_in[14];
    const float* outW  = (const float*)d_in[15];  const float* outB  = (const float*)d_in[16];
    const float* gW1   = (const float*)d_in[17];  const float* gB1   = (const float*)d_in[18];
    const float* gW2   = (const float*)d_in[19];  const float* gB2   = (const float*)d_in[20];
    const float* uW1   = (const float*)d_in[21];  const float* uB1   = (const float*)d_in[22];
    const float* uW2   = (const float*)d_in[23];  const float* uB2   = (const float*)d_in[24];
    const float* gnW1  = (const float*)d_in[25];  const float* gnB1  = (const float*)d_in[26];
    const float* gnW2  = (const float*)d_in[27];  const float* gnB2  = (const float*)d_in[28];
    const float* hW1   = (const float*)d_in[29];  const float* hB1   = (const float*)d_in[30];
    const float* hW2   = (const float*)d_in[31];  const float* hB2   = (const float*)d_in[32];
    float* out = (float*)d_out;

    char* ws = (char*)d_ws;
    size_t off = 0;
    auto alloc = [&](size_t bytes) -> void* {
        void* p = ws + off;
        off = (off + bytes + 255) & ~(size_t)255;
        return p;
    };
    u16* hidden = (u16*)alloc((size_t)KRR * 256 * 2);   // GNN overlay buffers
    u16* ctxb   = (u16*)alloc((size_t)KP * 256 * 2);
    u16* acat   = (u16*)alloc((size_t)KP * 512 * 2);
    u16* ghid   = (u16*)alloc((size_t)KP * 256 * 2);
    float* gate = (float*)alloc((size_t)KP * 256 * 4);
    u16* uhid   = (u16*)alloc((size_t)KP * 256 * 2);
    float* upd  = (float*)alloc((size_t)KP * 256 * 4);
    u16* wqk_g  = (u16*)alloc((size_t)KP * 1024 * 2);
    u16* wt_rp1 = (u16*)alloc(256 * 288 * 2);
    u16* wt_kv  = (u16*)alloc(512 * 256 * 2);
    u16* wt_qf  = (u16*)alloc(256 * 256 * 2);
    u16* wt_o   = (u16*)alloc(256 * 256 * 2);
    u16* wt_g1  = (u16*)alloc(256 * 512 * 2);
    u16* wt_g2  = (u16*)alloc(256 * 256 * 2);
    u16* wt_u1  = (u16*)alloc(256 * 256 * 2);
    u16* wt_u2  = (u16*)alloc(256 * 256 * 2);
    u16* wt_gn1 = (u16*)alloc(256 * 256 * 2);
    u16* wt_gn2 = (u16*)alloc(256 * 256 * 2);
    u16* wt_h1  = (u16*)alloc(256 * 256 * 2);
    u16* wt_qk  = (u16*)alloc(1024 * 256 * 2);
    float* Qf32 = (float*)alloc(256 * 256 * 4);
    float* Wk32 = (float*)alloc(256 * 256 * 4);
    float* bias_kv = (float*)alloc(512 * 4);
    float* bias_qf = (float*)alloc(256 * 4);
    float* bias_qk = (float*)alloc(1024 * 4);
    int*   winner    = (int*)alloc(NN * 4);
    int*   cnt       = (int*)alloc(NN * 4);
    int*   cursor    = (int*)alloc(NN * 4);
    int*   row_start = (int*)alloc((NN + 1) * 4);
    int*   bsums     = (int*)alloc(1024 * 4);
    float* isd       = (float*)alloc(NN * 4);
    int*   csr_src   = (int*)alloc((size_t)EE * 4);
    float* csr_w     = (float*)alloc((size_t)EE * 4);

    // GNN stage overlays hidden: 3 buffers of NP rows
    const size_t NPE = (size_t)NP * 256;
    u16* gZ0 = hidden;            // hb -> x2
    u16* gZ1 = hidden + NPE;      // x1 -> h2
    u16* gZ2 = hidden + 2 * NPE;  // h1 -> thid

    const int* esrc = edge;
    const int* edst = edge + EE;

    auto wtp = [&](const float* W, int ld, int coloff, int fi, int Kpad, u16* Wt) {
        wtpose_k<<<(256 * Kpad + 255) / 256, 256, 0, stream>>>(W, ld, coloff, fi, Kpad, Wt);
    };

    // ---- CSR prep ----
    hipMemsetAsync(cnt, 0, NN * 4, stream);
    hipMemsetAsync(cursor, 0, NN * 4, stream);
    edge_count_k<<<(EE + 255) / 256, 256, 0, stream>>>(edst, cnt, EE);
    isd_k<<<(NN + 255) / 256, 256, 0, stream>>>(cnt, isd, NN);
    int nb = (NN + SCANB - 1) / SCANB;
    scan1_k<<<nb, SCANB, 0, stream>>>(cnt, row_start, bsums, NN);
    scan2_k<<<1, 64, 0, stream>>>(bsums, nb);
    scan3_k<<<nb, SCANB, 0, stream>>>(row_start, bsums, NN, EE);
    csr_scatter_k<<<(EE + 255) / 256, 256, 0, stream>>>(esrc, edst, row_start, cursor, isd,
                                                        csr_src, csr_w, EE);

    // ---- weight prep ----
    wtp(rp_W1, 256, 0, 265, 288, wt_rp1);   // K-extended: z(256) + o(8) + score(1) + pad
    wfuse_k<<<256, 256, 0, stream>>>(rp_W2, inW, 768, 256, rp_b2, inB + 256,
                                     wt_kv, bias_kv, Wk32);
    wfuse_k<<<256, 256, 0, stream>>>(rp_W2, inW, 768, 512, rp_b2, inB + 512,
                                     wt_kv + 256 * 256, bias_kv + 256, nullptr);
    wfuse_k<<<256, 256, 0, stream>>>(qp_W, inW, 768, 0, qp_b, inB,
                                     wt_qf, bias_qf, Qf32);
    qkfuse_k<<<1024, 256, 0, stream>>>(Qf32, Wk32, bias_qf, wt_qk, bias_qk);
    wtp(outW, 256, 0, 256, 256, wt_o);
    wtp(gW1,  256, 0, 512, 512, wt_g1);
    wtp(gW2,  256, 0, 256, 256, wt_g2);
    wtp(uW1,  256, 0, 256, 256, wt_u1);
    wtp(uW2,  256, 0, 256, 256, wt_u2);
    wtp(gnW1, 256, 0, 256, 256, wt_gn1);
    wtp(gnW2, 256, 0, 256, 256, wt_gn2);
    wtp(hW1,  256, 0, 256, 256, wt_h1);
    gather_hq_k<<<(KKP + 3) / 4, 256, 0, stream>>>(h_cone, nids, acat);

    // ---- wqk = hq @ QKfused + bias  (query pushed through Wk; [KKP,1024]) ----
    gemm_bf_k<0, 1, 0, 0><<<dim3((KKP + 127) / 128, 8), 256, 0, stream>>>(
        acat, 512, KKP, 256, wt_qk, bias_qk, wqk_g, 1024, nullptr, nullptr, nullptr);

    // ---- fused retrieval megakernel -> ctx ----
    retrfuse_k<<<KRR / 128, 512, 0, stream>>>(
        z_retr, wt_rp1, rp_b1, o_retr, retr_score,
        wqk_g, wt_kv + 256 * 256, bias_kv + 256, ctxb);

    // ---- out-projection ----
    gemm_bf_k<0, 1, 0, 0><<<dim3((KKP + 127) / 128, 2), 256, 0, stream>>>(
        ctxb, 256, KKP, 256, wt_o, outB, acat + 256, 512, nullptr, nullptr, nullptr);

    // ---- gate / update ----
    gemm_bf_k<1, 1, 0, 0><<<dim3((KKP + 127) / 128, 2), 256, 0, stream>>>(
        acat, 512, KKP, 512, wt_g1, gB1, ghid, 256, nullptr, nullptr, nullptr);
    gemm_bf_k<2, 2, 0, 0><<<dim3((KKP + 127) / 128, 2), 256, 0, stream>>>(
        ghid, 256, KKP, 256, wt_g2, gB2, gate, 256, nullptr, nullptr, nullptr);
    gemm_bf_k<1, 1, 0, 0><<<dim3((KKP + 127) / 128, 2), 256, 0, stream>>>(
        acat + 256, 512, KKP, 256, wt_u1, uB1, uhid, 256, nullptr, nullptr, nullptr);
    gemm_bf_k<0, 2, 0, 0><<<dim3((KKP + 127) / 128, 2), 256, 0, stream>>>(
        uhid, 256, KKP, 256, wt_u2, uB2, upd, 256, nullptr, nullptr, nullptr);

    // ---- scatter into hb (bf16 copy of h_cone, winner rows overwritten) ----
    conv_f2b_k<<<(int)(((size_t)NN * 64 + 255) / 256), 256, 0, stream>>>(
        h_cone, gZ0, (size_t)NN * 64);
    hipMemsetAsync(winner, 0xFF, NN * 4, stream);
    winner_k<<<(KKP + 255) / 256, 256, 0, stream>>>(nids, winner);
    scatter_h_k<<<(KKP + 3) / 4, 256, 0, stream>>>(nids, winner, h_cone, gate, upd, gZ0);

    // ---- cone GNN ----
    gemm_bf_k<0, 1, 0, 0><<<dim3((NN + 127) / 128, 2), 256, 0, stream>>>(
        gZ0, 256, NN, 256, wt_gn1, gnB1, gZ1, 256, nullptr, nullptr, nullptr);       // x1
    gnn_agg_k<1><<<(NN + 3) / 4, 256, 0, stream>>>(gZ1, row_start, csr_src, csr_w, isd, gZ2); // h1
    gemm_bf_k<0, 1, 0, 0><<<dim3((NN + 127) / 128, 2), 256, 0, stream>>>(
        gZ2, 256, NN, 256, wt_gn2, gnB2, gZ0, 256, nullptr, nullptr, nullptr);       // x2
    gnn_agg_k<0><<<(NN + 3) / 4, 256, 0, stream>>>(gZ0, row_start, csr_src, csr_w, isd, gZ1); // h2
    gemm_bf_k<1, 1, 0, 0><<<dim3((NN + 127) / 128, 2), 256, 0, stream>>>(
        gZ1, 256, NN, 256, wt_h1, hB1, gZ2, 256, nullptr, nullptr, nullptr);         // thid
    head_out_k<<<(NN + 31) / 32, 256, 0, stream>>>(gZ2, hW2, hB2, teacher, out, NN);
}